// Round 2
// baseline (2199.247 us; speedup 1.0000x reference)
//
#include <hip/hip_runtime.h>
#include <hip/hip_bf16.h>

#define N_NODES 50000
#define N_EDGES 1600000
#define N_GRAPHS 64

// ---------------------------------------------------------------------------
// Graph-structure construction
// ---------------------------------------------------------------------------
__global__ void init_deg(int* deg) {
    int i = blockIdx.x * blockDim.x + threadIdx.x;
    if (i < N_NODES) deg[i] = 1;  // self-loop
}

__global__ void deg_count(const int* __restrict__ dst, int* __restrict__ deg) {
    int e = blockIdx.x * blockDim.x + threadIdx.x;
    if (e < N_EDGES) atomicAdd(&deg[dst[e]], 1);
}

__global__ void make_dinv(const int* __restrict__ deg, float* __restrict__ dinv) {
    int i = blockIdx.x * blockDim.x + threadIdx.x;
    if (i < N_NODES) dinv[i] = rsqrtf((float)deg[i]);
}

// single-block inclusive-scan over edge-only degrees -> rowstart[N+1], pos[N]
__global__ void scan_deg(const int* __restrict__ deg, int* __restrict__ rowstart,
                         int* __restrict__ pos) {
    __shared__ int sm[1024];
    __shared__ int carry_s;
    int t = threadIdx.x;
    if (t == 0) carry_s = 0;
    __syncthreads();
    for (int base = 0; base < N_NODES; base += 1024) {
        int i = base + t;
        int v = (i < N_NODES) ? (deg[i] - 1) : 0;  // exclude self loop
        sm[t] = v;
        __syncthreads();
        for (int off = 1; off < 1024; off <<= 1) {
            int prev = (t >= off) ? sm[t - off] : 0;
            __syncthreads();
            sm[t] += prev;
            __syncthreads();
        }
        int incl = sm[t];
        int carry = carry_s;
        int total = sm[1023];
        if (i < N_NODES) {
            int e = carry + incl - v;
            rowstart[i] = e;
            pos[i] = e;
        }
        __syncthreads();
        if (t == 0) carry_s = carry + total;
        __syncthreads();
    }
    if (t == 0) rowstart[N_NODES] = carry_s;
}

__global__ void csr_fill(const int* __restrict__ src, const int* __restrict__ dst,
                         const float* __restrict__ dinv, int* __restrict__ pos,
                         int* __restrict__ csr_src, float* __restrict__ csr_norm) {
    int e = blockIdx.x * blockDim.x + threadIdx.x;
    if (e >= N_EDGES) return;
    int s = src[e], d = dst[e];
    int slot = atomicAdd(&pos[d], 1);
    csr_src[slot] = s;
    csr_norm[slot] = dinv[s] * dinv[d];
}

// ---------------------------------------------------------------------------
// SGEMM: C[M,N] = A[M,K] @ B[K,N]   (BM=BN=128, BK=16, 256 thr, 8x8/thread)
// requires K%16==0, N%128==0
// ---------------------------------------------------------------------------
__launch_bounds__(256)
__global__ void sgemm128(const float* __restrict__ A, const float* __restrict__ B,
                         float* __restrict__ C, int M, int N, int K) {
    __shared__ float As[16][128];
    __shared__ float Bs[16][128];
    const int tid = threadIdx.x;
    const int tx = tid & 15;
    const int ty = tid >> 4;
    const int row0 = blockIdx.x * 128;
    const int col0 = blockIdx.y * 128;
    const int lr = tid >> 1;          // A row within tile (0..127)
    const int lk = (tid & 1) * 8;     // A k offset (0 or 8)
    const int bc = tid & 127;         // B col within tile
    const int bk = (tid >> 7) * 8;    // B k offset (0 or 8)
    float acc[8][8];
#pragma unroll
    for (int i = 0; i < 8; ++i)
#pragma unroll
        for (int j = 0; j < 8; ++j) acc[i][j] = 0.0f;

    for (int k0 = 0; k0 < K; k0 += 16) {
        // ---- load A tile (transposed into LDS) ----
        {
            int row = row0 + lr;
            float4 v0 = make_float4(0, 0, 0, 0), v1 = v0;
            if (row < M) {
                const float* ap = A + (size_t)row * K + k0 + lk;
                v0 = *(const float4*)ap;
                v1 = *(const float4*)(ap + 4);
            }
            As[lk + 0][lr] = v0.x; As[lk + 1][lr] = v0.y;
            As[lk + 2][lr] = v0.z; As[lk + 3][lr] = v0.w;
            As[lk + 4][lr] = v1.x; As[lk + 5][lr] = v1.y;
            As[lk + 6][lr] = v1.z; As[lk + 7][lr] = v1.w;
        }
        // ---- load B tile ----
        {
            const float* bp = B + (size_t)(k0 + bk) * N + col0 + bc;
#pragma unroll
            for (int u = 0; u < 8; ++u) Bs[bk + u][bc] = bp[(size_t)u * N];
        }
        __syncthreads();
#pragma unroll
        for (int k = 0; k < 16; ++k) {
            float4 a0 = *(const float4*)&As[k][ty * 8];
            float4 a1 = *(const float4*)&As[k][ty * 8 + 4];
            float4 b0 = *(const float4*)&Bs[k][tx * 8];
            float4 b1 = *(const float4*)&Bs[k][tx * 8 + 4];
            float a[8] = {a0.x, a0.y, a0.z, a0.w, a1.x, a1.y, a1.z, a1.w};
            float b[8] = {b0.x, b0.y, b0.z, b0.w, b1.x, b1.y, b1.z, b1.w};
#pragma unroll
            for (int i = 0; i < 8; ++i)
#pragma unroll
                for (int j = 0; j < 8; ++j) acc[i][j] += a[i] * b[j];
        }
        __syncthreads();
    }
#pragma unroll
    for (int i = 0; i < 8; ++i) {
        int row = row0 + ty * 8 + i;
        if (row < M) {
            float* cp = C + (size_t)row * N + col0 + tx * 8;
            *(float4*)cp = make_float4(acc[i][0], acc[i][1], acc[i][2], acc[i][3]);
            *(float4*)(cp + 4) = make_float4(acc[i][4], acc[i][5], acc[i][6], acc[i][7]);
        }
    }
}

// ---------------------------------------------------------------------------
// Edge aggregation: one wave per node.  out[i] = sum_{e: dst=i} h[src_e]*norm_e
//                   + h[i]*dinv[i]^2 + bias
// ---------------------------------------------------------------------------
template <int D>
__launch_bounds__(256)
__global__ void aggregate(const float* __restrict__ h, const int* __restrict__ rowstart,
                          const int* __restrict__ csr_src, const float* __restrict__ csr_norm,
                          const float* __restrict__ dinv, const float* __restrict__ bias,
                          float* __restrict__ out) {
    constexpr int V = D / 64;  // floats per lane (2 or 4)
    int w = (int)((blockIdx.x * blockDim.x + threadIdx.x) >> 6);
    int lane = threadIdx.x & 63;
    if (w >= N_NODES) return;
    float acc[V];
    float di = dinv[w];
    const float* hp = h + (size_t)w * D + lane * V;
#pragma unroll
    for (int v = 0; v < V; ++v) acc[v] = hp[v] * (di * di);
    int e0 = rowstart[w], e1 = rowstart[w + 1];
    for (int j = e0; j < e1; ++j) {
        int s = csr_src[j];
        float nm = csr_norm[j];
        const float* sp = h + (size_t)s * D + lane * V;
#pragma unroll
        for (int v = 0; v < V; ++v) acc[v] += sp[v] * nm;
    }
    float* op = out + (size_t)w * D + lane * V;
#pragma unroll
    for (int v = 0; v < V; ++v) op[v] = acc[v] + bias[lane * V + v];
}

// ---------------------------------------------------------------------------
// BatchNorm (training stats, biased var) + ReLU
// ---------------------------------------------------------------------------
template <int D>
__global__ void bn_stats(const float* __restrict__ h, float* __restrict__ stat) {
    int f = threadIdx.x;  // D threads
    int r0 = blockIdx.x * 128;
    int r1 = min(r0 + 128, N_NODES);
    float s = 0.f, s2 = 0.f;
    for (int r = r0; r < r1; ++r) {
        float v = h[(size_t)r * D + f];
        s += v;
        s2 += v * v;
    }
    atomicAdd(&stat[f], s);
    atomicAdd(&stat[D + f], s2);
}

template <int D>
__global__ void bn_finalize(const float* __restrict__ stat, const float* __restrict__ gamma,
                            const float* __restrict__ beta, float* __restrict__ ss) {
    int f = threadIdx.x;
    float m = stat[f] * (1.0f / N_NODES);
    float var = stat[D + f] * (1.0f / N_NODES) - m * m;
    float sc = gamma[f] * rsqrtf(var + 1e-5f);
    ss[f] = sc;
    ss[D + f] = beta[f] - m * sc;
}

template <int D>
__global__ void bn_apply_relu(float* __restrict__ h, const float* __restrict__ ss) {
    size_t i = (size_t)blockIdx.x * blockDim.x + threadIdx.x;
    if (i >= (size_t)N_NODES * D) return;
    int f = (int)(i & (D - 1));
    float v = h[i] * ss[f] + ss[D + f];
    h[i] = v > 0.f ? v : 0.f;
}

// ---------------------------------------------------------------------------
// Pool (batch is sorted) + FC head
// ---------------------------------------------------------------------------
__global__ void count_batch(const int* __restrict__ batch, int* __restrict__ cnt) {
    int i = blockIdx.x * blockDim.x + threadIdx.x;
    if (i < N_NODES) atomicAdd(&cnt[batch[i]], 1);
}

__global__ void pool_seg(const float* __restrict__ h, const int* __restrict__ batch,
                         float* __restrict__ psum) {
    int f = threadIdx.x;  // 256
    int r0 = blockIdx.x * 64;
    int r1 = min(r0 + 64, N_NODES);
    float acc = 0.f;
    int cur = batch[r0];
    for (int r = r0; r < r1; ++r) {
        int b = batch[r];
        if (b != cur) {
            atomicAdd(&psum[cur * 256 + f], acc);
            acc = 0.f;
            cur = b;
        }
        acc += h[(size_t)r * 256 + f];
    }
    atomicAdd(&psum[cur * 256 + f], acc);
}

__global__ void pool_div(const float* __restrict__ psum, const int* __restrict__ cnt,
                         float* __restrict__ g) {
    int i = blockIdx.x * 256 + threadIdx.x;  // 64*256
    int b = i >> 8;
    float c = (float)max(cnt[b], 1);
    g[i] = psum[i] / c;
}

__global__ void fc_relu_k(const float* __restrict__ X, const float* __restrict__ W,
                          const float* __restrict__ b, float* __restrict__ Y, int K, int N) {
    int col = blockIdx.x * blockDim.x + threadIdx.x;
    int row = blockIdx.y;
    if (col >= N) return;
    float acc = b[col];
    const float* x = X + (size_t)row * K;
    for (int k = 0; k < K; ++k) acc += x[k] * W[(size_t)k * N + col];
    Y[(size_t)row * N + col] = acc > 0.f ? acc : 0.f;
}

__global__ void fc_out_k(const float* __restrict__ X, const float* __restrict__ W,
                         const float* __restrict__ b, float* __restrict__ Y, int K, int N) {
    int col = threadIdx.x;
    int row = blockIdx.x;
    float acc = b[col];
    const float* x = X + (size_t)row * K;
    for (int k = 0; k < K; ++k) acc += x[k] * W[(size_t)k * N + col];
    Y[(size_t)row * N + col] = acc;
}

// ---------------------------------------------------------------------------
extern "C" void kernel_launch(void* const* d_in, const int* in_sizes, int n_in,
                              void* d_out, int out_size, void* d_ws, size_t ws_size,
                              hipStream_t stream) {
    const float* x     = (const float*)d_in[0];
    const int*   ei    = (const int*)d_in[1];   // [2][E]: row0=src, row1=dst
    const int*   batch = (const int*)d_in[2];
    const float* Wg0 = (const float*)d_in[3],  *bg0 = (const float*)d_in[4];
    const float* gamma0 = (const float*)d_in[5], *beta0 = (const float*)d_in[6];
    const float* Wg1 = (const float*)d_in[7],  *bg1 = (const float*)d_in[8];
    const float* gamma1 = (const float*)d_in[9], *beta1 = (const float*)d_in[10];
    const float* Wg2 = (const float*)d_in[11], *bg2 = (const float*)d_in[12];
    const float* gamma2 = (const float*)d_in[13], *beta2 = (const float*)d_in[14];
    const float* Wf0 = (const float*)d_in[15], *bf0 = (const float*)d_in[16];
    const float* Wf1 = (const float*)d_in[17], *bf1 = (const float*)d_in[18];
    float* out = (float*)d_out;

    // ---- workspace carve (~116.4 MB) ----
    size_t off = 0;
    auto alloc = [&](size_t bytes) {
        void* p = (char*)d_ws + off;
        off += (bytes + 255) & ~(size_t)255;
        return p;
    };
    float* hA       = (float*)alloc((size_t)N_NODES * 256 * 4);
    float* hB       = (float*)alloc((size_t)N_NODES * 256 * 4);
    int*   csr_src  = (int*)alloc((size_t)N_EDGES * 4);
    float* csr_norm = (float*)alloc((size_t)N_EDGES * 4);
    int*   deg      = (int*)alloc((size_t)N_NODES * 4);
    float* dinv     = (float*)alloc((size_t)N_NODES * 4);
    int*   rowstart = (int*)alloc((size_t)(N_NODES + 1) * 4);
    int*   pos      = (int*)alloc((size_t)N_NODES * 4);
    float* bnstat   = (float*)alloc(2 * 256 * 4);
    float* bnss     = (float*)alloc(2 * 256 * 4);
    float* psum     = (float*)alloc(64 * 256 * 4);
    int*   pcount   = (int*)alloc(64 * 4);
    float* gpool    = (float*)alloc(64 * 256 * 4);
    float* g1       = (float*)alloc(64 * 1024 * 4);
    (void)ws_size;

    const int TPB = 256;
    const int nb_nodes = (N_NODES + TPB - 1) / TPB;
    const int nb_edges = (N_EDGES + TPB - 1) / TPB;

    // ---- graph structure ----
    init_deg<<<nb_nodes, TPB, 0, stream>>>(deg);
    deg_count<<<nb_edges, TPB, 0, stream>>>(ei + N_EDGES, deg);
    make_dinv<<<nb_nodes, TPB, 0, stream>>>(deg, dinv);
    scan_deg<<<1, 1024, 0, stream>>>(deg, rowstart, pos);
    csr_fill<<<nb_edges, TPB, 0, stream>>>(ei, ei + N_EDGES, dinv, pos, csr_src, csr_norm);

    const int MB = (N_NODES + 127) / 128;  // 391
    const int agg_blocks = (N_NODES * 64 + TPB - 1) / TPB;  // 12500

    // ---- layer 0: 1280 -> 128 ----
    sgemm128<<<dim3(MB, 1), 256, 0, stream>>>(x, Wg0, hA, N_NODES, 128, 1280);
    aggregate<128><<<agg_blocks, 256, 0, stream>>>(hA, rowstart, csr_src, csr_norm, dinv, bg0, hB);
    hipMemsetAsync(bnstat, 0, 2 * 128 * 4, stream);
    bn_stats<128><<<(N_NODES + 127) / 128, 128, 0, stream>>>(hB, bnstat);
    bn_finalize<128><<<1, 128, 0, stream>>>(bnstat, gamma0, beta0, bnss);
    bn_apply_relu<128><<<(N_NODES * 128) / 256, 256, 0, stream>>>(hB, bnss);

    // ---- layer 1: 128 -> 256 ----
    sgemm128<<<dim3(MB, 2), 256, 0, stream>>>(hB, Wg1, hA, N_NODES, 256, 128);
    aggregate<256><<<agg_blocks, 256, 0, stream>>>(hA, rowstart, csr_src, csr_norm, dinv, bg1, hB);
    hipMemsetAsync(bnstat, 0, 2 * 256 * 4, stream);
    bn_stats<256><<<(N_NODES + 127) / 128, 256, 0, stream>>>(hB, bnstat);
    bn_finalize<256><<<1, 256, 0, stream>>>(bnstat, gamma1, beta1, bnss);
    bn_apply_relu<256><<<(N_NODES * 256) / 256, 256, 0, stream>>>(hB, bnss);

    // ---- layer 2: 256 -> 256 ----
    sgemm128<<<dim3(MB, 2), 256, 0, stream>>>(hB, Wg2, hA, N_NODES, 256, 256);
    aggregate<256><<<agg_blocks, 256, 0, stream>>>(hA, rowstart, csr_src, csr_norm, dinv, bg2, hB);
    hipMemsetAsync(bnstat, 0, 2 * 256 * 4, stream);
    bn_stats<256><<<(N_NODES + 127) / 128, 256, 0, stream>>>(hB, bnstat);
    bn_finalize<256><<<1, 256, 0, stream>>>(bnstat, gamma2, beta2, bnss);
    bn_apply_relu<256><<<(N_NODES * 256) / 256, 256, 0, stream>>>(hB, bnss);

    // ---- global mean pool ----
    hipMemsetAsync(psum, 0, 64 * 256 * 4, stream);
    hipMemsetAsync(pcount, 0, 64 * 4, stream);
    count_batch<<<nb_nodes, TPB, 0, stream>>>(batch, pcount);
    pool_seg<<<(N_NODES + 63) / 64, 256, 0, stream>>>(hB, batch, psum);
    pool_div<<<64, 256, 0, stream>>>(psum, pcount, gpool);

    // ---- FC head ----
    fc_relu_k<<<dim3(4, 64), 256, 0, stream>>>(gpool, Wf0, bf0, g1, 256, 1024);
    fc_out_k<<<64, 128, 0, stream>>>(g1, Wf1, bf1, out, 1024, 128);
}

// Round 3
// 1747.262 us; speedup vs baseline: 1.2587x; 1.2587x over previous
//
#include <hip/hip_runtime.h>
#include <hip/hip_bf16.h>

#define N_NODES 50000
#define N_EDGES 1600000
#define N_GRAPHS 64

// ---------------------------------------------------------------------------
// Graph-structure construction
// ---------------------------------------------------------------------------
__global__ void init_deg(int* deg) {
    int i = blockIdx.x * blockDim.x + threadIdx.x;
    if (i < N_NODES) deg[i] = 1;  // self-loop
}

__global__ void deg_count(const int* __restrict__ dst, int* __restrict__ deg) {
    int e = blockIdx.x * blockDim.x + threadIdx.x;
    if (e < N_EDGES) atomicAdd(&deg[dst[e]], 1);
}

__global__ void make_dinv(const int* __restrict__ deg, float* __restrict__ dinv) {
    int i = blockIdx.x * blockDim.x + threadIdx.x;
    if (i < N_NODES) dinv[i] = rsqrtf((float)deg[i]);
}

// single-block scan over edge-only degrees -> rowstart[N+1], pos[N]
// wave-shuffle inclusive scan, 3 barriers per 1024-chunk
__global__ void scan_deg(const int* __restrict__ deg, int* __restrict__ rowstart,
                         int* __restrict__ pos) {
    __shared__ int wsum[16];
    __shared__ int carry_s;
    const int t = threadIdx.x;
    const int lane = t & 63;
    const int w = t >> 6;
    if (t == 0) carry_s = 0;
    __syncthreads();
    for (int base = 0; base < N_NODES; base += 1024) {
        int i = base + t;
        int v = (i < N_NODES) ? (deg[i] - 1) : 0;  // exclude self loop
        // inclusive wave scan
        int s = v;
#pragma unroll
        for (int off = 1; off < 64; off <<= 1) {
            int n = __shfl_up(s, off, 64);
            if (lane >= off) s += n;
        }
        if (lane == 63) wsum[w] = s;
        __syncthreads();
        if (w == 0) {
            int ws = (lane < 16) ? wsum[lane] : 0;
#pragma unroll
            for (int off = 1; off < 16; off <<= 1) {
                int n = __shfl_up(ws, off, 64);
                if (lane >= off) ws += n;
            }
            if (lane < 16) wsum[lane] = ws;
        }
        __syncthreads();
        int waveoff = (w == 0) ? 0 : wsum[w - 1];
        int carry = carry_s;
        int excl = carry + waveoff + s - v;
        if (i < N_NODES) {
            rowstart[i] = excl;
            pos[i] = excl;
        }
        __syncthreads();
        if (t == 0) carry_s = carry + wsum[15];
        __syncthreads();
    }
    if (t == 0) rowstart[N_NODES] = carry_s;
}

__global__ void csr_fill(const int* __restrict__ src, const int* __restrict__ dst,
                         const float* __restrict__ dinv, int* __restrict__ pos,
                         int* __restrict__ csr_src, float* __restrict__ csr_norm) {
    int e = blockIdx.x * blockDim.x + threadIdx.x;
    if (e >= N_EDGES) return;
    int s = src[e], d = dst[e];
    int slot = atomicAdd(&pos[d], 1);
    csr_src[slot] = s;
    csr_norm[slot] = dinv[s] * dinv[d];
}

// ---------------------------------------------------------------------------
// SGEMM: C[M,N] = A[M,K] @ B[K,N]   (BM=BN=128, BK=16, 256 thr, 8x8/thread)
// requires K%16==0, N%128==0
// ---------------------------------------------------------------------------
__launch_bounds__(256)
__global__ void sgemm128(const float* __restrict__ A, const float* __restrict__ B,
                         float* __restrict__ C, int M, int N, int K) {
    __shared__ float As[16][128];
    __shared__ float Bs[16][128];
    const int tid = threadIdx.x;
    const int tx = tid & 15;
    const int ty = tid >> 4;
    const int row0 = blockIdx.x * 128;
    const int col0 = blockIdx.y * 128;
    const int lr = tid >> 1;          // A row within tile (0..127)
    const int lk = (tid & 1) * 8;     // A k offset (0 or 8)
    const int bc = tid & 127;         // B col within tile
    const int bk = (tid >> 7) * 8;    // B k offset (0 or 8)
    float acc[8][8];
#pragma unroll
    for (int i = 0; i < 8; ++i)
#pragma unroll
        for (int j = 0; j < 8; ++j) acc[i][j] = 0.0f;

    for (int k0 = 0; k0 < K; k0 += 16) {
        // ---- load A tile (transposed into LDS) ----
        {
            int row = row0 + lr;
            float4 v0 = make_float4(0, 0, 0, 0), v1 = v0;
            if (row < M) {
                const float* ap = A + (size_t)row * K + k0 + lk;
                v0 = *(const float4*)ap;
                v1 = *(const float4*)(ap + 4);
            }
            As[lk + 0][lr] = v0.x; As[lk + 1][lr] = v0.y;
            As[lk + 2][lr] = v0.z; As[lk + 3][lr] = v0.w;
            As[lk + 4][lr] = v1.x; As[lk + 5][lr] = v1.y;
            As[lk + 6][lr] = v1.z; As[lk + 7][lr] = v1.w;
        }
        // ---- load B tile ----
        {
            const float* bp = B + (size_t)(k0 + bk) * N + col0 + bc;
#pragma unroll
            for (int u = 0; u < 8; ++u) Bs[bk + u][bc] = bp[(size_t)u * N];
        }
        __syncthreads();
#pragma unroll
        for (int k = 0; k < 16; ++k) {
            float4 a0 = *(const float4*)&As[k][ty * 8];
            float4 a1 = *(const float4*)&As[k][ty * 8 + 4];
            float4 b0 = *(const float4*)&Bs[k][tx * 8];
            float4 b1 = *(const float4*)&Bs[k][tx * 8 + 4];
            float a[8] = {a0.x, a0.y, a0.z, a0.w, a1.x, a1.y, a1.z, a1.w};
            float b[8] = {b0.x, b0.y, b0.z, b0.w, b1.x, b1.y, b1.z, b1.w};
#pragma unroll
            for (int i = 0; i < 8; ++i)
#pragma unroll
                for (int j = 0; j < 8; ++j) acc[i][j] += a[i] * b[j];
        }
        __syncthreads();
    }
#pragma unroll
    for (int i = 0; i < 8; ++i) {
        int row = row0 + ty * 8 + i;
        if (row < M) {
            float* cp = C + (size_t)row * N + col0 + tx * 8;
            *(float4*)cp = make_float4(acc[i][0], acc[i][1], acc[i][2], acc[i][3]);
            *(float4*)(cp + 4) = make_float4(acc[i][4], acc[i][5], acc[i][6], acc[i][7]);
        }
    }
}

// ---------------------------------------------------------------------------
// Edge aggregation: one wave per node.  out[i] = sum_{e: dst=i} h[src_e]*norm_e
//                   + h[i]*dinv[i]^2 + bias
// ---------------------------------------------------------------------------
template <int D>
__launch_bounds__(256)
__global__ void aggregate(const float* __restrict__ h, const int* __restrict__ rowstart,
                          const int* __restrict__ csr_src, const float* __restrict__ csr_norm,
                          const float* __restrict__ dinv, const float* __restrict__ bias,
                          float* __restrict__ out) {
    constexpr int V = D / 64;  // floats per lane (2 or 4)
    int w = (int)((blockIdx.x * blockDim.x + threadIdx.x) >> 6);
    int lane = threadIdx.x & 63;
    if (w >= N_NODES) return;
    float acc[V];
    float di = dinv[w];
    const float* hp = h + (size_t)w * D + lane * V;
#pragma unroll
    for (int v = 0; v < V; ++v) acc[v] = hp[v] * (di * di);
    int e0 = rowstart[w], e1 = rowstart[w + 1];
    for (int j = e0; j < e1; ++j) {
        int s = csr_src[j];
        float nm = csr_norm[j];
        const float* sp = h + (size_t)s * D + lane * V;
#pragma unroll
        for (int v = 0; v < V; ++v) acc[v] += sp[v] * nm;
    }
    float* op = out + (size_t)w * D + lane * V;
#pragma unroll
    for (int v = 0; v < V; ++v) op[v] = acc[v] + bias[lane * V + v];
}

// ---------------------------------------------------------------------------
// BatchNorm (training stats, biased var) + ReLU
// ---------------------------------------------------------------------------
template <int D>
__global__ void bn_stats(const float* __restrict__ h, float* __restrict__ stat) {
    int f = threadIdx.x;  // D threads
    int r0 = blockIdx.x * 128;
    int r1 = min(r0 + 128, N_NODES);
    float s = 0.f, s2 = 0.f;
    for (int r = r0; r < r1; ++r) {
        float v = h[(size_t)r * D + f];
        s += v;
        s2 += v * v;
    }
    atomicAdd(&stat[f], s);
    atomicAdd(&stat[D + f], s2);
}

template <int D>
__global__ void bn_finalize(const float* __restrict__ stat, const float* __restrict__ gamma,
                            const float* __restrict__ beta, float* __restrict__ ss) {
    int f = threadIdx.x;
    float m = stat[f] * (1.0f / N_NODES);
    float var = stat[D + f] * (1.0f / N_NODES) - m * m;
    float sc = gamma[f] * rsqrtf(var + 1e-5f);
    ss[f] = sc;
    ss[D + f] = beta[f] - m * sc;
}

template <int D>
__global__ void bn_apply_relu(float* __restrict__ h, const float* __restrict__ ss) {
    size_t i = (size_t)blockIdx.x * blockDim.x + threadIdx.x;
    if (i >= (size_t)N_NODES * D) return;
    int f = (int)(i & (D - 1));
    float v = h[i] * ss[f] + ss[D + f];
    h[i] = v > 0.f ? v : 0.f;
}

// ---------------------------------------------------------------------------
// Pool (batch is sorted) + FC head
// ---------------------------------------------------------------------------
__global__ void count_batch(const int* __restrict__ batch, int* __restrict__ cnt) {
    int i = blockIdx.x * blockDim.x + threadIdx.x;
    if (i < N_NODES) atomicAdd(&cnt[batch[i]], 1);
}

__global__ void pool_seg(const float* __restrict__ h, const int* __restrict__ batch,
                         float* __restrict__ psum) {
    int f = threadIdx.x;  // 256
    int r0 = blockIdx.x * 64;
    int r1 = min(r0 + 64, N_NODES);
    float acc = 0.f;
    int cur = batch[r0];
    for (int r = r0; r < r1; ++r) {
        int b = batch[r];
        if (b != cur) {
            atomicAdd(&psum[cur * 256 + f], acc);
            acc = 0.f;
            cur = b;
        }
        acc += h[(size_t)r * 256 + f];
    }
    atomicAdd(&psum[cur * 256 + f], acc);
}

__global__ void pool_div(const float* __restrict__ psum, const int* __restrict__ cnt,
                         float* __restrict__ g) {
    int i = blockIdx.x * 256 + threadIdx.x;  // 64*256
    int b = i >> 8;
    float c = (float)max(cnt[b], 1);
    g[i] = psum[i] / c;
}

// ---- FC head: split-K with atomic accumulation (high TLP) ----
__global__ void fc_init(const float* __restrict__ b, float* __restrict__ Y, int rows, int N) {
    int i = blockIdx.x * blockDim.x + threadIdx.x;
    if (i < rows * N) Y[i] = b[i % N];
}

// grid: (N/TPB, rows, K/KC); block TPB threads (one per col)
__global__ void fc_splitk(const float* __restrict__ X, const float* __restrict__ W,
                          float* __restrict__ Y, int K, int N, int KC) {
    int col = blockIdx.x * blockDim.x + threadIdx.x;
    int row = blockIdx.y;
    int k0 = blockIdx.z * KC;
    float acc = 0.f;
    const float* x = X + (size_t)row * K + k0;
    const float* w = W + (size_t)k0 * N + col;
#pragma unroll 8
    for (int k = 0; k < KC; ++k) acc += x[k] * w[(size_t)k * N];
    atomicAdd(&Y[(size_t)row * N + col], acc);
}

__global__ void relu_inplace(float* __restrict__ Y, int n) {
    int i = blockIdx.x * blockDim.x + threadIdx.x;
    if (i < n) Y[i] = Y[i] > 0.f ? Y[i] : 0.f;
}

// ---------------------------------------------------------------------------
extern "C" void kernel_launch(void* const* d_in, const int* in_sizes, int n_in,
                              void* d_out, int out_size, void* d_ws, size_t ws_size,
                              hipStream_t stream) {
    const float* x     = (const float*)d_in[0];
    const int*   ei    = (const int*)d_in[1];   // [2][E]: row0=src, row1=dst
    const int*   batch = (const int*)d_in[2];
    const float* Wg0 = (const float*)d_in[3],  *bg0 = (const float*)d_in[4];
    const float* gamma0 = (const float*)d_in[5], *beta0 = (const float*)d_in[6];
    const float* Wg1 = (const float*)d_in[7],  *bg1 = (const float*)d_in[8];
    const float* gamma1 = (const float*)d_in[9], *beta1 = (const float*)d_in[10];
    const float* Wg2 = (const float*)d_in[11], *bg2 = (const float*)d_in[12];
    const float* gamma2 = (const float*)d_in[13], *beta2 = (const float*)d_in[14];
    const float* Wf0 = (const float*)d_in[15], *bf0 = (const float*)d_in[16];
    const float* Wf1 = (const float*)d_in[17], *bf1 = (const float*)d_in[18];
    float* out = (float*)d_out;

    // ---- workspace carve ----
    size_t off = 0;
    auto alloc = [&](size_t bytes) {
        void* p = (char*)d_ws + off;
        off += (bytes + 255) & ~(size_t)255;
        return p;
    };
    float* hA       = (float*)alloc((size_t)N_NODES * 256 * 4);
    float* hB       = (float*)alloc((size_t)N_NODES * 256 * 4);
    int*   csr_src  = (int*)alloc((size_t)N_EDGES * 4);
    float* csr_norm = (float*)alloc((size_t)N_EDGES * 4);
    int*   deg      = (int*)alloc((size_t)N_NODES * 4);
    float* dinv     = (float*)alloc((size_t)N_NODES * 4);
    int*   rowstart = (int*)alloc((size_t)(N_NODES + 1) * 4);
    int*   pos      = (int*)alloc((size_t)N_NODES * 4);
    float* bnstat   = (float*)alloc(2 * 256 * 4);
    float* bnss     = (float*)alloc(2 * 256 * 4);
    float* psum     = (float*)alloc(64 * 256 * 4);
    int*   pcount   = (int*)alloc(64 * 4);
    float* gpool    = (float*)alloc(64 * 256 * 4);
    float* g1       = (float*)alloc(64 * 1024 * 4);
    (void)ws_size;

    const int TPB = 256;
    const int nb_nodes = (N_NODES + TPB - 1) / TPB;
    const int nb_edges = (N_EDGES + TPB - 1) / TPB;

    // ---- graph structure ----
    init_deg<<<nb_nodes, TPB, 0, stream>>>(deg);
    deg_count<<<nb_edges, TPB, 0, stream>>>(ei + N_EDGES, deg);
    make_dinv<<<nb_nodes, TPB, 0, stream>>>(deg, dinv);
    scan_deg<<<1, 1024, 0, stream>>>(deg, rowstart, pos);
    csr_fill<<<nb_edges, TPB, 0, stream>>>(ei, ei + N_EDGES, dinv, pos, csr_src, csr_norm);

    const int MB = (N_NODES + 127) / 128;  // 391
    const int agg_blocks = (N_NODES * 64 + TPB - 1) / TPB;  // 12500

    // ---- layer 0: 1280 -> 128 ----
    sgemm128<<<dim3(MB, 1), 256, 0, stream>>>(x, Wg0, hA, N_NODES, 128, 1280);
    aggregate<128><<<agg_blocks, 256, 0, stream>>>(hA, rowstart, csr_src, csr_norm, dinv, bg0, hB);
    hipMemsetAsync(bnstat, 0, 2 * 128 * 4, stream);
    bn_stats<128><<<(N_NODES + 127) / 128, 128, 0, stream>>>(hB, bnstat);
    bn_finalize<128><<<1, 128, 0, stream>>>(bnstat, gamma0, beta0, bnss);
    bn_apply_relu<128><<<(N_NODES * 128) / 256, 256, 0, stream>>>(hB, bnss);

    // ---- layer 1: 128 -> 256 ----
    sgemm128<<<dim3(MB, 2), 256, 0, stream>>>(hB, Wg1, hA, N_NODES, 256, 128);
    aggregate<256><<<agg_blocks, 256, 0, stream>>>(hA, rowstart, csr_src, csr_norm, dinv, bg1, hB);
    hipMemsetAsync(bnstat, 0, 2 * 256 * 4, stream);
    bn_stats<256><<<(N_NODES + 127) / 128, 256, 0, stream>>>(hB, bnstat);
    bn_finalize<256><<<1, 256, 0, stream>>>(bnstat, gamma1, beta1, bnss);
    bn_apply_relu<256><<<(N_NODES * 256) / 256, 256, 0, stream>>>(hB, bnss);

    // ---- layer 2: 256 -> 256 ----
    sgemm128<<<dim3(MB, 2), 256, 0, stream>>>(hB, Wg2, hA, N_NODES, 256, 256);
    aggregate<256><<<agg_blocks, 256, 0, stream>>>(hA, rowstart, csr_src, csr_norm, dinv, bg2, hB);
    hipMemsetAsync(bnstat, 0, 2 * 256 * 4, stream);
    bn_stats<256><<<(N_NODES + 127) / 128, 256, 0, stream>>>(hB, bnstat);
    bn_finalize<256><<<1, 256, 0, stream>>>(bnstat, gamma2, beta2, bnss);
    bn_apply_relu<256><<<(N_NODES * 256) / 256, 256, 0, stream>>>(hB, bnss);

    // ---- global mean pool ----
    hipMemsetAsync(psum, 0, 64 * 256 * 4, stream);
    hipMemsetAsync(pcount, 0, 64 * 4, stream);
    count_batch<<<nb_nodes, TPB, 0, stream>>>(batch, pcount);
    pool_seg<<<(N_NODES + 63) / 64, 256, 0, stream>>>(hB, batch, psum);
    pool_div<<<64, 256, 0, stream>>>(psum, pcount, gpool);

    // ---- FC head (split-K, atomic accumulate) ----
    // FC0: [64,256] @ [256,1024] -> g1 [64,1024], then ReLU
    fc_init<<<(64 * 1024 + 255) / 256, 256, 0, stream>>>(bf0, g1, 64, 1024);
    fc_splitk<<<dim3(4, 64, 4), 256, 0, stream>>>(gpool, Wf0, g1, 256, 1024, 64);
    relu_inplace<<<(64 * 1024 + 255) / 256, 256, 0, stream>>>(g1, 64 * 1024);
    // FC1: [64,1024] @ [1024,128] -> out [64,128]
    fc_init<<<(64 * 128 + 255) / 256, 256, 0, stream>>>(bf1, out, 64, 128);
    fc_splitk<<<dim3(1, 64, 16), 128, 0, stream>>>(g1, Wf1, out, 1024, 128, 64);
}

// Round 4
// 1412.897 us; speedup vs baseline: 1.5566x; 1.2367x over previous
//
#include <hip/hip_runtime.h>
#include <hip/hip_bf16.h>

#define N_NODES 50000
#define N_EDGES 1600000
#define N_GRAPHS 64

typedef _Float16 f16;
typedef _Float16 f16x8 __attribute__((ext_vector_type(8)));
typedef _Float16 f16x4 __attribute__((ext_vector_type(4)));
typedef _Float16 f16x2 __attribute__((ext_vector_type(2)));
typedef float f32x4 __attribute__((ext_vector_type(4)));

// ---------------------------------------------------------------------------
// Graph-structure construction
// ---------------------------------------------------------------------------
__global__ void init_deg(int* deg) {
    int i = blockIdx.x * blockDim.x + threadIdx.x;
    if (i < N_NODES) deg[i] = 1;  // self-loop
}

__global__ void deg_count(const int* __restrict__ dst, int* __restrict__ deg) {
    int e = blockIdx.x * blockDim.x + threadIdx.x;
    if (e < N_EDGES) atomicAdd(&deg[dst[e]], 1);
}

__global__ void make_dinv(const int* __restrict__ deg, float* __restrict__ dinv) {
    int i = blockIdx.x * blockDim.x + threadIdx.x;
    if (i < N_NODES) dinv[i] = rsqrtf((float)deg[i]);
}

// single-block scan over edge-only degrees -> rowstart[N+1], pos[N]
__global__ void scan_deg(const int* __restrict__ deg, int* __restrict__ rowstart,
                         int* __restrict__ pos) {
    __shared__ int wsum[16];
    __shared__ int carry_s;
    const int t = threadIdx.x;
    const int lane = t & 63;
    const int w = t >> 6;
    if (t == 0) carry_s = 0;
    __syncthreads();
    for (int base = 0; base < N_NODES; base += 1024) {
        int i = base + t;
        int v = (i < N_NODES) ? (deg[i] - 1) : 0;  // exclude self loop
        int s = v;
#pragma unroll
        for (int off = 1; off < 64; off <<= 1) {
            int n = __shfl_up(s, off, 64);
            if (lane >= off) s += n;
        }
        if (lane == 63) wsum[w] = s;
        __syncthreads();
        if (w == 0) {
            int ws = (lane < 16) ? wsum[lane] : 0;
#pragma unroll
            for (int off = 1; off < 16; off <<= 1) {
                int n = __shfl_up(ws, off, 64);
                if (lane >= off) ws += n;
            }
            if (lane < 16) wsum[lane] = ws;
        }
        __syncthreads();
        int waveoff = (w == 0) ? 0 : wsum[w - 1];
        int carry = carry_s;
        int excl = carry + waveoff + s - v;
        if (i < N_NODES) {
            rowstart[i] = excl;
            pos[i] = excl;
        }
        __syncthreads();
        if (t == 0) carry_s = carry + wsum[15];
        __syncthreads();
    }
    if (t == 0) rowstart[N_NODES] = carry_s;
}

__global__ void csr_fill(const int* __restrict__ src, const int* __restrict__ dst,
                         const float* __restrict__ dinv, int* __restrict__ pos,
                         int* __restrict__ csr_src, float* __restrict__ csr_norm) {
    int e = blockIdx.x * blockDim.x + threadIdx.x;
    if (e >= N_EDGES) return;
    int s = src[e], d = dst[e];
    int slot = atomicAdd(&pos[d], 1);
    csr_src[slot] = s;
    csr_norm[slot] = dinv[s] * dinv[d];
}

// ---------------------------------------------------------------------------
// Weight cast+transpose: Wt[n][k] = (f16) W[k][n]
// ---------------------------------------------------------------------------
__global__ void cast_w(const float* __restrict__ W, f16* __restrict__ Wt, int K, int N) {
    int i = blockIdx.x * blockDim.x + threadIdx.x;
    if (i >= K * N) return;
    int k = i % K, n = i / K;
    Wt[i] = (f16)W[(size_t)k * N + n];
}

// ---------------------------------------------------------------------------
// MFMA GEMM, layer 0: A[M,K] fp32 (cast in-register), Bt[N=128][K] f16,
// C16[M,128] f16.  One wave per 32 rows, no LDS.
// frag layouts (16x16x32): A/B: idx=lane&15, k=(lane>>4)*8+j ; D: col=lane&15,
// row=(lane>>4)*4+reg.
// ---------------------------------------------------------------------------
__launch_bounds__(256)
__global__ void gemm_x_f16(const float* __restrict__ A, const f16* __restrict__ Bt,
                           f16* __restrict__ C16, int M, int K) {
    const int wave = (int)((blockIdx.x * blockDim.x + threadIdx.x) >> 6);
    const int lane = threadIdx.x & 63;
    const int m0 = wave * 32;
    if (m0 >= M) return;
    const int r = lane & 15, q = lane >> 4;
    int row0 = m0 + r;       int row0c = row0 < M ? row0 : M - 1;
    int row1 = m0 + 16 + r;  int row1c = row1 < M ? row1 : M - 1;
    const float* a0 = A + (size_t)row0c * K + q * 8;
    const float* a1 = A + (size_t)row1c * K + q * 8;
    const f16* bp = Bt + (size_t)r * K + q * 8;

    f32x4 acc[2][8];
#pragma unroll
    for (int i = 0; i < 2; ++i)
#pragma unroll
        for (int j = 0; j < 8; ++j) acc[i][j] = (f32x4){0.f, 0.f, 0.f, 0.f};

    for (int k0 = 0; k0 < K; k0 += 32) {
        f16x8 af[2];
        {
            float4 u = *(const float4*)(a0 + k0);
            float4 v = *(const float4*)(a0 + k0 + 4);
            af[0] = (f16x8){(f16)u.x, (f16)u.y, (f16)u.z, (f16)u.w,
                            (f16)v.x, (f16)v.y, (f16)v.z, (f16)v.w};
            u = *(const float4*)(a1 + k0);
            v = *(const float4*)(a1 + k0 + 4);
            af[1] = (f16x8){(f16)u.x, (f16)u.y, (f16)u.z, (f16)u.w,
                            (f16)v.x, (f16)v.y, (f16)v.z, (f16)v.w};
        }
#pragma unroll
        for (int ni = 0; ni < 8; ++ni) {
            f16x8 bf = *(const f16x8*)(bp + (size_t)ni * 16 * K + k0);
            acc[0][ni] = __builtin_amdgcn_mfma_f32_16x16x32_f16(af[0], bf, acc[0][ni], 0, 0, 0);
            acc[1][ni] = __builtin_amdgcn_mfma_f32_16x16x32_f16(af[1], bf, acc[1][ni], 0, 0, 0);
        }
    }
#pragma unroll
    for (int mi = 0; mi < 2; ++mi)
#pragma unroll
        for (int j = 0; j < 4; ++j) {
            int row = m0 + mi * 16 + q * 4 + j;
            if (row < M) {
                f16* cp = C16 + (size_t)row * 128 + r;
#pragma unroll
                for (int ni = 0; ni < 8; ++ni) cp[ni * 16] = (f16)acc[mi][ni][j];
            }
        }
}

// ---------------------------------------------------------------------------
// MFMA GEMM, layers 1/2: A16[M,K] f16, Bt[N][K] f16, C16[M,N] f16.
// wave = 32 rows x 128 cols; blockIdx.y = column 128-block.
// ---------------------------------------------------------------------------
template <int K>
__launch_bounds__(256)
__global__ void gemm_h_f16(const f16* __restrict__ A16, const f16* __restrict__ Bt,
                           f16* __restrict__ C16, int M, int N) {
    const int wave = (int)((blockIdx.x * blockDim.x + threadIdx.x) >> 6);
    const int lane = threadIdx.x & 63;
    const int m0 = wave * 32;
    if (m0 >= M) return;
    const int col0 = blockIdx.y * 128;
    const int r = lane & 15, q = lane >> 4;
    int row0 = m0 + r;       int row0c = row0 < M ? row0 : M - 1;
    int row1 = m0 + 16 + r;  int row1c = row1 < M ? row1 : M - 1;
    const f16* a0 = A16 + (size_t)row0c * K + q * 8;
    const f16* a1 = A16 + (size_t)row1c * K + q * 8;
    const f16* bp = Bt + (size_t)(col0 + r) * K + q * 8;

    f32x4 acc[2][8];
#pragma unroll
    for (int i = 0; i < 2; ++i)
#pragma unroll
        for (int j = 0; j < 8; ++j) acc[i][j] = (f32x4){0.f, 0.f, 0.f, 0.f};

#pragma unroll
    for (int k0 = 0; k0 < K; k0 += 32) {
        f16x8 af0 = *(const f16x8*)(a0 + k0);
        f16x8 af1 = *(const f16x8*)(a1 + k0);
#pragma unroll
        for (int ni = 0; ni < 8; ++ni) {
            f16x8 bf = *(const f16x8*)(bp + (size_t)ni * 16 * K + k0);
            acc[0][ni] = __builtin_amdgcn_mfma_f32_16x16x32_f16(af0, bf, acc[0][ni], 0, 0, 0);
            acc[1][ni] = __builtin_amdgcn_mfma_f32_16x16x32_f16(af1, bf, acc[1][ni], 0, 0, 0);
        }
    }
#pragma unroll
    for (int mi = 0; mi < 2; ++mi)
#pragma unroll
        for (int j = 0; j < 4; ++j) {
            int row = m0 + mi * 16 + q * 4 + j;
            if (row < M) {
                f16* cp = C16 + (size_t)row * N + col0 + r;
#pragma unroll
                for (int ni = 0; ni < 8; ++ni) cp[ni * 16] = (f16)acc[mi][ni][j];
            }
        }
}

// ---------------------------------------------------------------------------
// Edge aggregation (f16 gather, fp32 accumulate): one wave per node.
// out[i] = sum_{e: dst=i} h[src_e]*norm_e + h[i]*dinv_i^2 + bias
// ---------------------------------------------------------------------------
template <int D>
__launch_bounds__(256)
__global__ void aggregate(const f16* __restrict__ h, const int* __restrict__ rowstart,
                          const int* __restrict__ csr_src, const float* __restrict__ csr_norm,
                          const float* __restrict__ dinv, const float* __restrict__ bias,
                          float* __restrict__ out) {
    constexpr int V = D / 64;  // f16 per lane (2 or 4)
    int w = (int)((blockIdx.x * blockDim.x + threadIdx.x) >> 6);
    int lane = threadIdx.x & 63;
    if (w >= N_NODES) return;
    float acc[V];
    float di = dinv[w];
    const f16* hp = h + (size_t)w * D + lane * V;
#pragma unroll
    for (int v = 0; v < V; ++v) acc[v] = (float)hp[v] * (di * di);
    int e0 = rowstart[w], e1 = rowstart[w + 1];
    for (int j = e0; j < e1; ++j) {
        int s = csr_src[j];
        float nm = csr_norm[j];
        const f16* sp = h + (size_t)s * D + lane * V;
#pragma unroll
        for (int v = 0; v < V; ++v) acc[v] += (float)sp[v] * nm;
    }
    float* op = out + (size_t)w * D + lane * V;
#pragma unroll
    for (int v = 0; v < V; ++v) op[v] = acc[v] + bias[lane * V + v];
}

// ---------------------------------------------------------------------------
// BatchNorm (training stats, biased var) + ReLU; emits fp32 (for pool/BN) and
// f16 (for next GEMM).
// ---------------------------------------------------------------------------
template <int D>
__global__ void bn_stats(const float* __restrict__ h, float* __restrict__ stat) {
    int f = threadIdx.x;  // D threads
    int r0 = blockIdx.x * 128;
    int r1 = min(r0 + 128, N_NODES);
    float s = 0.f, s2 = 0.f;
    for (int r = r0; r < r1; ++r) {
        float v = h[(size_t)r * D + f];
        s += v;
        s2 += v * v;
    }
    atomicAdd(&stat[f], s);
    atomicAdd(&stat[D + f], s2);
}

template <int D>
__global__ void bn_finalize(const float* __restrict__ stat, const float* __restrict__ gamma,
                            const float* __restrict__ beta, float* __restrict__ ss) {
    int f = threadIdx.x;
    float m = stat[f] * (1.0f / N_NODES);
    float var = stat[D + f] * (1.0f / N_NODES) - m * m;
    float sc = gamma[f] * rsqrtf(var + 1e-5f);
    ss[f] = sc;
    ss[D + f] = beta[f] - m * sc;
}

template <int D>
__global__ void bn_apply_relu(float* __restrict__ h, const float* __restrict__ ss,
                              f16* __restrict__ h16) {
    size_t i = (size_t)blockIdx.x * blockDim.x + threadIdx.x;
    if (i >= (size_t)N_NODES * D) return;
    int f = (int)(i & (D - 1));
    float v = h[i] * ss[f] + ss[D + f];
    v = v > 0.f ? v : 0.f;
    h[i] = v;
    h16[i] = (f16)v;
}

// ---------------------------------------------------------------------------
// Pool (batch is sorted) + FC head
// ---------------------------------------------------------------------------
__global__ void count_batch(const int* __restrict__ batch, int* __restrict__ cnt) {
    int i = blockIdx.x * blockDim.x + threadIdx.x;
    if (i < N_NODES) atomicAdd(&cnt[batch[i]], 1);
}

__global__ void pool_seg(const float* __restrict__ h, const int* __restrict__ batch,
                         float* __restrict__ psum) {
    int f = threadIdx.x;  // 256
    int r0 = blockIdx.x * 64;
    int r1 = min(r0 + 64, N_NODES);
    float acc = 0.f;
    int cur = batch[r0];
    for (int r = r0; r < r1; ++r) {
        int b = batch[r];
        if (b != cur) {
            atomicAdd(&psum[cur * 256 + f], acc);
            acc = 0.f;
            cur = b;
        }
        acc += h[(size_t)r * 256 + f];
    }
    atomicAdd(&psum[cur * 256 + f], acc);
}

__global__ void pool_div(const float* __restrict__ psum, const int* __restrict__ cnt,
                         float* __restrict__ g) {
    int i = blockIdx.x * 256 + threadIdx.x;  // 64*256
    int b = i >> 8;
    float c = (float)max(cnt[b], 1);
    g[i] = psum[i] / c;
}

// ---- FC head: split-K with atomic accumulation (high TLP) ----
__global__ void fc_init(const float* __restrict__ b, float* __restrict__ Y, int rows, int N) {
    int i = blockIdx.x * blockDim.x + threadIdx.x;
    if (i < rows * N) Y[i] = b[i % N];
}

__global__ void fc_splitk(const float* __restrict__ X, const float* __restrict__ W,
                          float* __restrict__ Y, int K, int N, int KC) {
    int col = blockIdx.x * blockDim.x + threadIdx.x;
    int row = blockIdx.y;
    int k0 = blockIdx.z * KC;
    float acc = 0.f;
    const float* x = X + (size_t)row * K + k0;
    const float* w = W + (size_t)k0 * N + col;
#pragma unroll 8
    for (int k = 0; k < KC; ++k) acc += x[k] * w[(size_t)k * N];
    atomicAdd(&Y[(size_t)row * N + col], acc);
}

__global__ void relu_inplace(float* __restrict__ Y, int n) {
    int i = blockIdx.x * blockDim.x + threadIdx.x;
    if (i < n) Y[i] = Y[i] > 0.f ? Y[i] : 0.f;
}

// ---------------------------------------------------------------------------
extern "C" void kernel_launch(void* const* d_in, const int* in_sizes, int n_in,
                              void* d_out, int out_size, void* d_ws, size_t ws_size,
                              hipStream_t stream) {
    const float* x     = (const float*)d_in[0];
    const int*   ei    = (const int*)d_in[1];   // [2][E]: row0=src, row1=dst
    const int*   batch = (const int*)d_in[2];
    const float* Wg0 = (const float*)d_in[3],  *bg0 = (const float*)d_in[4];
    const float* gamma0 = (const float*)d_in[5], *beta0 = (const float*)d_in[6];
    const float* Wg1 = (const float*)d_in[7],  *bg1 = (const float*)d_in[8];
    const float* gamma1 = (const float*)d_in[9], *beta1 = (const float*)d_in[10];
    const float* Wg2 = (const float*)d_in[11], *bg2 = (const float*)d_in[12];
    const float* gamma2 = (const float*)d_in[13], *beta2 = (const float*)d_in[14];
    const float* Wf0 = (const float*)d_in[15], *bf0 = (const float*)d_in[16];
    const float* Wf1 = (const float*)d_in[17], *bf1 = (const float*)d_in[18];
    float* out = (float*)d_out;

    // ---- workspace carve (~117 MB) ----
    size_t off = 0;
    auto alloc = [&](size_t bytes) {
        void* p = (char*)d_ws + off;
        off += (bytes + 255) & ~(size_t)255;
        return p;
    };
    f16*   hA16     = (f16*)alloc((size_t)N_NODES * 256 * 2);   // GEMM out (gather src)
    float* hB       = (float*)alloc((size_t)N_NODES * 256 * 4); // aggregate out / BN
    f16*   h16      = (f16*)alloc((size_t)N_NODES * 256 * 2);   // BN out, next GEMM in
    int*   csr_src  = (int*)alloc((size_t)N_EDGES * 4);
    float* csr_norm = (float*)alloc((size_t)N_EDGES * 4);
    int*   deg      = (int*)alloc((size_t)N_NODES * 4);
    float* dinv     = (float*)alloc((size_t)N_NODES * 4);
    int*   rowstart = (int*)alloc((size_t)(N_NODES + 1) * 4);
    int*   pos      = (int*)alloc((size_t)N_NODES * 4);
    float* bnstat   = (float*)alloc(2 * 256 * 4);
    float* bnss     = (float*)alloc(2 * 256 * 4);
    float* psum     = (float*)alloc(64 * 256 * 4);
    int*   pcount   = (int*)alloc(64 * 4);
    float* gpool    = (float*)alloc(64 * 256 * 4);
    float* g1       = (float*)alloc(64 * 1024 * 4);
    f16*   W0t      = (f16*)alloc((size_t)1280 * 128 * 2);
    f16*   W1t      = (f16*)alloc((size_t)128 * 256 * 2);
    f16*   W2t      = (f16*)alloc((size_t)256 * 256 * 2);
    (void)ws_size;

    const int TPB = 256;
    const int nb_nodes = (N_NODES + TPB - 1) / TPB;
    const int nb_edges = (N_EDGES + TPB - 1) / TPB;

    // ---- graph structure + weight casts ----
    init_deg<<<nb_nodes, TPB, 0, stream>>>(deg);
    deg_count<<<nb_edges, TPB, 0, stream>>>(ei + N_EDGES, deg);
    make_dinv<<<nb_nodes, TPB, 0, stream>>>(deg, dinv);
    scan_deg<<<1, 1024, 0, stream>>>(deg, rowstart, pos);
    csr_fill<<<nb_edges, TPB, 0, stream>>>(ei, ei + N_EDGES, dinv, pos, csr_src, csr_norm);
    cast_w<<<(1280 * 128 + 255) / 256, 256, 0, stream>>>(Wg0, W0t, 1280, 128);
    cast_w<<<(128 * 256 + 255) / 256, 256, 0, stream>>>(Wg1, W1t, 128, 256);
    cast_w<<<(256 * 256 + 255) / 256, 256, 0, stream>>>(Wg2, W2t, 256, 256);

    const int gemm_blocks = ((N_NODES + 31) / 32 * 64 + TPB - 1) / TPB;  // 391
    const int agg_blocks = (N_NODES * 64 + TPB - 1) / TPB;               // 12500

    // ---- layer 0: 1280 -> 128 ----
    gemm_x_f16<<<gemm_blocks, TPB, 0, stream>>>(x, W0t, hA16, N_NODES, 1280);
    aggregate<128><<<agg_blocks, TPB, 0, stream>>>(hA16, rowstart, csr_src, csr_norm, dinv, bg0, hB);
    hipMemsetAsync(bnstat, 0, 2 * 128 * 4, stream);
    bn_stats<128><<<(N_NODES + 127) / 128, 128, 0, stream>>>(hB, bnstat);
    bn_finalize<128><<<1, 128, 0, stream>>>(bnstat, gamma0, beta0, bnss);
    bn_apply_relu<128><<<(N_NODES * 128) / 256, 256, 0, stream>>>(hB, bnss, h16);

    // ---- layer 1: 128 -> 256 ----
    gemm_h_f16<128><<<dim3(gemm_blocks, 2), TPB, 0, stream>>>(h16, W1t, hA16, N_NODES, 256);
    aggregate<256><<<agg_blocks, TPB, 0, stream>>>(hA16, rowstart, csr_src, csr_norm, dinv, bg1, hB);
    hipMemsetAsync(bnstat, 0, 2 * 256 * 4, stream);
    bn_stats<256><<<(N_NODES + 127) / 128, 256, 0, stream>>>(hB, bnstat);
    bn_finalize<256><<<1, 256, 0, stream>>>(bnstat, gamma1, beta1, bnss);
    bn_apply_relu<256><<<(N_NODES * 256) / 256, 256, 0, stream>>>(hB, bnss, h16);

    // ---- layer 2: 256 -> 256 ----
    gemm_h_f16<256><<<dim3(gemm_blocks, 2), TPB, 0, stream>>>(h16, W2t, hA16, N_NODES, 256);
    aggregate<256><<<agg_blocks, TPB, 0, stream>>>(hA16, rowstart, csr_src, csr_norm, dinv, bg2, hB);
    hipMemsetAsync(bnstat, 0, 2 * 256 * 4, stream);
    bn_stats<256><<<(N_NODES + 127) / 128, 256, 0, stream>>>(hB, bnstat);
    bn_finalize<256><<<1, 256, 0, stream>>>(bnstat, gamma2, beta2, bnss);
    bn_apply_relu<256><<<(N_NODES * 256) / 256, 256, 0, stream>>>(hB, bnss, h16);

    // ---- global mean pool ----
    hipMemsetAsync(psum, 0, 64 * 256 * 4, stream);
    hipMemsetAsync(pcount, 0, 64 * 4, stream);
    count_batch<<<nb_nodes, TPB, 0, stream>>>(batch, pcount);
    pool_seg<<<(N_NODES + 63) / 64, 256, 0, stream>>>(hB, batch, psum);
    pool_div<<<64, 256, 0, stream>>>(psum, pcount, gpool);

    // ---- FC head (split-K, atomic accumulate) ----
    fc_init<<<(64 * 1024 + 255) / 256, 256, 0, stream>>>(bf0, g1, 64, 1024);
    fc_splitk<<<dim3(4, 64, 4), 256, 0, stream>>>(gpool, Wf0, g1, 256, 1024, 64);
    relu_inplace<<<(64 * 1024 + 255) / 256, 256, 0, stream>>>(g1, 64 * 1024);
    fc_init<<<(64 * 128 + 255) / 256, 256, 0, stream>>>(bf1, out, 64, 128);
    fc_splitk<<<dim3(1, 64, 16), 128, 0, stream>>>(g1, Wf1, out, 1024, 128, 64);
}

// Round 5
// 1185.674 us; speedup vs baseline: 1.8549x; 1.1916x over previous
//
#include <hip/hip_runtime.h>
#include <hip/hip_bf16.h>

#define N_NODES 50000
#define N_EDGES 1600000
#define N_GRAPHS 64

typedef _Float16 f16;
typedef _Float16 f16x8 __attribute__((ext_vector_type(8)));
typedef _Float16 f16x4 __attribute__((ext_vector_type(4)));
typedef _Float16 f16x2 __attribute__((ext_vector_type(2)));
typedef float f32x4 __attribute__((ext_vector_type(4)));

// ---------------------------------------------------------------------------
// Graph-structure construction
// ---------------------------------------------------------------------------
__global__ void init_deg(int* deg) {
    int i = blockIdx.x * blockDim.x + threadIdx.x;
    if (i < N_NODES) deg[i] = 1;  // self-loop
}

__global__ void deg_count(const int* __restrict__ dst, int* __restrict__ deg) {
    int e = blockIdx.x * blockDim.x + threadIdx.x;
    if (e < N_EDGES) atomicAdd(&deg[dst[e]], 1);
}

__global__ void make_dinv(const int* __restrict__ deg, float* __restrict__ dinv) {
    int i = blockIdx.x * blockDim.x + threadIdx.x;
    if (i < N_NODES) dinv[i] = rsqrtf((float)deg[i]);
}

// single-block scan over edge-only degrees -> rowstart[N+1], pos[N]
__global__ void scan_deg(const int* __restrict__ deg, int* __restrict__ rowstart,
                         int* __restrict__ pos) {
    __shared__ int wsum[16];
    __shared__ int carry_s;
    const int t = threadIdx.x;
    const int lane = t & 63;
    const int w = t >> 6;
    if (t == 0) carry_s = 0;
    __syncthreads();
    for (int base = 0; base < N_NODES; base += 1024) {
        int i = base + t;
        int v = (i < N_NODES) ? (deg[i] - 1) : 0;  // exclude self loop
        int s = v;
#pragma unroll
        for (int off = 1; off < 64; off <<= 1) {
            int n = __shfl_up(s, off, 64);
            if (lane >= off) s += n;
        }
        if (lane == 63) wsum[w] = s;
        __syncthreads();
        if (w == 0) {
            int ws = (lane < 16) ? wsum[lane] : 0;
#pragma unroll
            for (int off = 1; off < 16; off <<= 1) {
                int n = __shfl_up(ws, off, 64);
                if (lane >= off) ws += n;
            }
            if (lane < 16) wsum[lane] = ws;
        }
        __syncthreads();
        int waveoff = (w == 0) ? 0 : wsum[w - 1];
        int carry = carry_s;
        int excl = carry + waveoff + s - v;
        if (i < N_NODES) {
            rowstart[i] = excl;
            pos[i] = excl;
        }
        __syncthreads();
        if (t == 0) carry_s = carry + wsum[15];
        __syncthreads();
    }
    if (t == 0) rowstart[N_NODES] = carry_s;
}

__global__ void csr_fill(const int* __restrict__ src, const int* __restrict__ dst,
                         const float* __restrict__ dinv, int* __restrict__ pos,
                         int* __restrict__ csr_src, float* __restrict__ csr_norm) {
    int e = blockIdx.x * blockDim.x + threadIdx.x;
    if (e >= N_EDGES) return;
    int s = src[e], d = dst[e];
    int slot = atomicAdd(&pos[d], 1);
    csr_src[slot] = s;
    csr_norm[slot] = dinv[s] * dinv[d];
}

// ---------------------------------------------------------------------------
// Weight cast+transpose: Wt[n][k] = (f16) W[k][n]
// ---------------------------------------------------------------------------
__global__ void cast_w(const float* __restrict__ W, f16* __restrict__ Wt, int K, int N) {
    int i = blockIdx.x * blockDim.x + threadIdx.x;
    if (i >= K * N) return;
    int k = i % K, n = i / K;
    Wt[i] = (f16)W[(size_t)k * N + n];
}

// ---------------------------------------------------------------------------
// MFMA GEMM, layer 0: A[M,K] fp32 (cast in-register), Bt[N=128][K] f16,
// C16[M,128] f16.  One wave per 32 rows, no LDS.
// ---------------------------------------------------------------------------
__launch_bounds__(256)
__global__ void gemm_x_f16(const float* __restrict__ A, const f16* __restrict__ Bt,
                           f16* __restrict__ C16, int M, int K) {
    const int wave = (int)((blockIdx.x * blockDim.x + threadIdx.x) >> 6);
    const int lane = threadIdx.x & 63;
    const int m0 = wave * 32;
    if (m0 >= M) return;
    const int r = lane & 15, q = lane >> 4;
    int row0 = m0 + r;       int row0c = row0 < M ? row0 : M - 1;
    int row1 = m0 + 16 + r;  int row1c = row1 < M ? row1 : M - 1;
    const float* a0 = A + (size_t)row0c * K + q * 8;
    const float* a1 = A + (size_t)row1c * K + q * 8;
    const f16* bp = Bt + (size_t)r * K + q * 8;

    f32x4 acc[2][8];
#pragma unroll
    for (int i = 0; i < 2; ++i)
#pragma unroll
        for (int j = 0; j < 8; ++j) acc[i][j] = (f32x4){0.f, 0.f, 0.f, 0.f};

    for (int k0 = 0; k0 < K; k0 += 32) {
        f16x8 af[2];
        {
            float4 u = *(const float4*)(a0 + k0);
            float4 v = *(const float4*)(a0 + k0 + 4);
            af[0] = (f16x8){(f16)u.x, (f16)u.y, (f16)u.z, (f16)u.w,
                            (f16)v.x, (f16)v.y, (f16)v.z, (f16)v.w};
            u = *(const float4*)(a1 + k0);
            v = *(const float4*)(a1 + k0 + 4);
            af[1] = (f16x8){(f16)u.x, (f16)u.y, (f16)u.z, (f16)u.w,
                            (f16)v.x, (f16)v.y, (f16)v.z, (f16)v.w};
        }
#pragma unroll
        for (int ni = 0; ni < 8; ++ni) {
            f16x8 bf = *(const f16x8*)(bp + (size_t)ni * 16 * K + k0);
            acc[0][ni] = __builtin_amdgcn_mfma_f32_16x16x32_f16(af[0], bf, acc[0][ni], 0, 0, 0);
            acc[1][ni] = __builtin_amdgcn_mfma_f32_16x16x32_f16(af[1], bf, acc[1][ni], 0, 0, 0);
        }
    }
#pragma unroll
    for (int mi = 0; mi < 2; ++mi)
#pragma unroll
        for (int j = 0; j < 4; ++j) {
            int row = m0 + mi * 16 + q * 4 + j;
            if (row < M) {
                f16* cp = C16 + (size_t)row * 128 + r;
#pragma unroll
                for (int ni = 0; ni < 8; ++ni) cp[ni * 16] = (f16)acc[mi][ni][j];
            }
        }
}

// ---------------------------------------------------------------------------
// MFMA GEMM, layers 1/2: A16[M,K] f16, Bt[N][K] f16, C16[M,N] f16.
// ---------------------------------------------------------------------------
template <int K>
__launch_bounds__(256)
__global__ void gemm_h_f16(const f16* __restrict__ A16, const f16* __restrict__ Bt,
                           f16* __restrict__ C16, int M, int N) {
    const int wave = (int)((blockIdx.x * blockDim.x + threadIdx.x) >> 6);
    const int lane = threadIdx.x & 63;
    const int m0 = wave * 32;
    if (m0 >= M) return;
    const int col0 = blockIdx.y * 128;
    const int r = lane & 15, q = lane >> 4;
    int row0 = m0 + r;       int row0c = row0 < M ? row0 : M - 1;
    int row1 = m0 + 16 + r;  int row1c = row1 < M ? row1 : M - 1;
    const f16* a0 = A16 + (size_t)row0c * K + q * 8;
    const f16* a1 = A16 + (size_t)row1c * K + q * 8;
    const f16* bp = Bt + (size_t)(col0 + r) * K + q * 8;

    f32x4 acc[2][8];
#pragma unroll
    for (int i = 0; i < 2; ++i)
#pragma unroll
        for (int j = 0; j < 8; ++j) acc[i][j] = (f32x4){0.f, 0.f, 0.f, 0.f};

#pragma unroll
    for (int k0 = 0; k0 < K; k0 += 32) {
        f16x8 af0 = *(const f16x8*)(a0 + k0);
        f16x8 af1 = *(const f16x8*)(a1 + k0);
#pragma unroll
        for (int ni = 0; ni < 8; ++ni) {
            f16x8 bf = *(const f16x8*)(bp + (size_t)ni * 16 * K + k0);
            acc[0][ni] = __builtin_amdgcn_mfma_f32_16x16x32_f16(af0, bf, acc[0][ni], 0, 0, 0);
            acc[1][ni] = __builtin_amdgcn_mfma_f32_16x16x32_f16(af1, bf, acc[1][ni], 0, 0, 0);
        }
    }
#pragma unroll
    for (int mi = 0; mi < 2; ++mi)
#pragma unroll
        for (int j = 0; j < 4; ++j) {
            int row = m0 + mi * 16 + q * 4 + j;
            if (row < M) {
                f16* cp = C16 + (size_t)row * N + col0 + r;
#pragma unroll
                for (int ni = 0; ni < 8; ++ni) cp[ni * 16] = (f16)acc[mi][ni][j];
            }
        }
}

// ---------------------------------------------------------------------------
// Edge aggregation (f16 gather, fp32 accumulate): one wave per node.
// ---------------------------------------------------------------------------
template <int D>
__launch_bounds__(256)
__global__ void aggregate(const f16* __restrict__ h, const int* __restrict__ rowstart,
                          const int* __restrict__ csr_src, const float* __restrict__ csr_norm,
                          const float* __restrict__ dinv, const float* __restrict__ bias,
                          float* __restrict__ out) {
    constexpr int V = D / 64;  // f16 per lane (2 or 4)
    int w = (int)((blockIdx.x * blockDim.x + threadIdx.x) >> 6);
    int lane = threadIdx.x & 63;
    if (w >= N_NODES) return;
    float acc[V];
    float di = dinv[w];
    const f16* hp = h + (size_t)w * D + lane * V;
#pragma unroll
    for (int v = 0; v < V; ++v) acc[v] = (float)hp[v] * (di * di);
    int e0 = rowstart[w], e1 = rowstart[w + 1];
    for (int j = e0; j < e1; ++j) {
        int s = csr_src[j];
        float nm = csr_norm[j];
        const f16* sp = h + (size_t)s * D + lane * V;
#pragma unroll
        for (int v = 0; v < V; ++v) acc[v] += (float)sp[v] * nm;
    }
    float* op = out + (size_t)w * D + lane * V;
#pragma unroll
    for (int v = 0; v < V; ++v) op[v] = acc[v] + bias[lane * V + v];
}

// ---------------------------------------------------------------------------
// BatchNorm (training stats, biased var) + ReLU
// ---------------------------------------------------------------------------
template <int D>
__global__ void bn_stats(const float* __restrict__ h, float* __restrict__ stat) {
    int f = threadIdx.x;  // D threads
    int r0 = blockIdx.x * 128;
    int r1 = min(r0 + 128, N_NODES);
    float s = 0.f, s2 = 0.f;
    for (int r = r0; r < r1; ++r) {
        float v = h[(size_t)r * D + f];
        s += v;
        s2 += v * v;
    }
    atomicAdd(&stat[f], s);
    atomicAdd(&stat[D + f], s2);
}

template <int D>
__global__ void bn_finalize(const float* __restrict__ stat, const float* __restrict__ gamma,
                            const float* __restrict__ beta, float* __restrict__ ss) {
    int f = threadIdx.x;
    float m = stat[f] * (1.0f / N_NODES);
    float var = stat[D + f] * (1.0f / N_NODES) - m * m;
    float sc = gamma[f] * rsqrtf(var + 1e-5f);
    ss[f] = sc;
    ss[D + f] = beta[f] - m * sc;
}

template <int D>
__global__ void bn_apply_relu(float* __restrict__ h, const float* __restrict__ ss,
                              f16* __restrict__ h16) {
    size_t i = (size_t)blockIdx.x * blockDim.x + threadIdx.x;
    if (i >= (size_t)N_NODES * D) return;
    int f = (int)(i & (D - 1));
    float v = h[i] * ss[f] + ss[D + f];
    v = v > 0.f ? v : 0.f;
    h[i] = v;
    h16[i] = (f16)v;
}

// ---------------------------------------------------------------------------
// Pool (batch is sorted) + FC head
// ---------------------------------------------------------------------------
// counts via binary search over the SORTED batch array — zero atomics
__global__ void count_batch_bs(const int* __restrict__ batch, int* __restrict__ cnt) {
    int g = threadIdx.x;  // one block, 64 threads
    if (g >= N_GRAPHS) return;
    int lo = 0, hi = N_NODES;
    while (lo < hi) { int mid = (lo + hi) >> 1; if (batch[mid] < g) lo = mid + 1; else hi = mid; }
    int b0 = lo;
    lo = 0; hi = N_NODES;
    while (lo < hi) { int mid = (lo + hi) >> 1; if (batch[mid] < g + 1) lo = mid + 1; else hi = mid; }
    cnt[g] = lo - b0;
}

__global__ void pool_seg(const float* __restrict__ h, const int* __restrict__ batch,
                         float* __restrict__ psum) {
    int f = threadIdx.x;  // 256
    int r0 = blockIdx.x * 64;
    int r1 = min(r0 + 64, N_NODES);
    float acc = 0.f;
    int cur = batch[r0];
    for (int r = r0; r < r1; ++r) {
        int b = batch[r];
        if (b != cur) {
            atomicAdd(&psum[cur * 256 + f], acc);
            acc = 0.f;
            cur = b;
        }
        acc += h[(size_t)r * 256 + f];
    }
    atomicAdd(&psum[cur * 256 + f], acc);
}

__global__ void pool_div(const float* __restrict__ psum, const int* __restrict__ cnt,
                         float* __restrict__ g) {
    int i = blockIdx.x * 256 + threadIdx.x;  // 64*256
    int b = i >> 8;
    float c = (float)max(cnt[b], 1);
    g[i] = psum[i] / c;
}

// ---- FC head: split-K with atomic accumulation (high TLP) ----
__global__ void fc_init(const float* __restrict__ b, float* __restrict__ Y, int rows, int N) {
    int i = blockIdx.x * blockDim.x + threadIdx.x;
    if (i < rows * N) Y[i] = b[i % N];
}

__global__ void fc_splitk(const float* __restrict__ X, const float* __restrict__ W,
                          float* __restrict__ Y, int K, int N, int KC) {
    int col = blockIdx.x * blockDim.x + threadIdx.x;
    int row = blockIdx.y;
    int k0 = blockIdx.z * KC;
    float acc = 0.f;
    const float* x = X + (size_t)row * K + k0;
    const float* w = W + (size_t)k0 * N + col;
#pragma unroll 8
    for (int k = 0; k < KC; ++k) acc += x[k] * w[(size_t)k * N];
    atomicAdd(&Y[(size_t)row * N + col], acc);
}

__global__ void relu_inplace(float* __restrict__ Y, int n) {
    int i = blockIdx.x * blockDim.x + threadIdx.x;
    if (i < n) Y[i] = Y[i] > 0.f ? Y[i] : 0.f;
}

// ---------------------------------------------------------------------------
extern "C" void kernel_launch(void* const* d_in, const int* in_sizes, int n_in,
                              void* d_out, int out_size, void* d_ws, size_t ws_size,
                              hipStream_t stream) {
    const float* x     = (const float*)d_in[0];
    const int*   ei    = (const int*)d_in[1];   // [2][E]: row0=src, row1=dst
    const int*   batch = (const int*)d_in[2];
    const float* Wg0 = (const float*)d_in[3],  *bg0 = (const float*)d_in[4];
    const float* gamma0 = (const float*)d_in[5], *beta0 = (const float*)d_in[6];
    const float* Wg1 = (const float*)d_in[7],  *bg1 = (const float*)d_in[8];
    const float* gamma1 = (const float*)d_in[9], *beta1 = (const float*)d_in[10];
    const float* Wg2 = (const float*)d_in[11], *bg2 = (const float*)d_in[12];
    const float* gamma2 = (const float*)d_in[13], *beta2 = (const float*)d_in[14];
    const float* Wf0 = (const float*)d_in[15], *bf0 = (const float*)d_in[16];
    const float* Wf1 = (const float*)d_in[17], *bf1 = (const float*)d_in[18];
    float* out = (float*)d_out;

    // ---- workspace carve (~117 MB) ----
    size_t off = 0;
    auto alloc = [&](size_t bytes) {
        void* p = (char*)d_ws + off;
        off += (bytes + 255) & ~(size_t)255;
        return p;
    };
    f16*   hA16     = (f16*)alloc((size_t)N_NODES * 256 * 2);   // GEMM out (gather src)
    float* hB       = (float*)alloc((size_t)N_NODES * 256 * 4); // aggregate out / BN
    f16*   h16      = (f16*)alloc((size_t)N_NODES * 256 * 2);   // BN out, next GEMM in
    int*   csr_src  = (int*)alloc((size_t)N_EDGES * 4);
    float* csr_norm = (float*)alloc((size_t)N_EDGES * 4);
    int*   deg      = (int*)alloc((size_t)N_NODES * 4);
    float* dinv     = (float*)alloc((size_t)N_NODES * 4);
    int*   rowstart = (int*)alloc((size_t)(N_NODES + 1) * 4);
    int*   pos      = (int*)alloc((size_t)N_NODES * 4);
    float* bnstat   = (float*)alloc(2 * 256 * 4);
    float* bnss     = (float*)alloc(2 * 256 * 4);
    float* psum     = (float*)alloc(64 * 256 * 4);
    int*   pcount   = (int*)alloc(64 * 4);
    float* gpool    = (float*)alloc(64 * 256 * 4);
    float* g1       = (float*)alloc(64 * 1024 * 4);
    f16*   W0t      = (f16*)alloc((size_t)1280 * 128 * 2);
    f16*   W1t      = (f16*)alloc((size_t)128 * 256 * 2);
    f16*   W2t      = (f16*)alloc((size_t)256 * 256 * 2);
    (void)ws_size;

    const int TPB = 256;
    const int nb_nodes = (N_NODES + TPB - 1) / TPB;
    const int nb_edges = (N_EDGES + TPB - 1) / TPB;

    // ---- graph structure + weight casts ----
    init_deg<<<nb_nodes, TPB, 0, stream>>>(deg);
    deg_count<<<nb_edges, TPB, 0, stream>>>(ei + N_EDGES, deg);
    make_dinv<<<nb_nodes, TPB, 0, stream>>>(deg, dinv);
    scan_deg<<<1, 1024, 0, stream>>>(deg, rowstart, pos);
    csr_fill<<<nb_edges, TPB, 0, stream>>>(ei, ei + N_EDGES, dinv, pos, csr_src, csr_norm);
    cast_w<<<(1280 * 128 + 255) / 256, 256, 0, stream>>>(Wg0, W0t, 1280, 128);
    cast_w<<<(128 * 256 + 255) / 256, 256, 0, stream>>>(Wg1, W1t, 128, 256);
    cast_w<<<(256 * 256 + 255) / 256, 256, 0, stream>>>(Wg2, W2t, 256, 256);

    const int gemm_blocks = ((N_NODES + 31) / 32 * 64 + TPB - 1) / TPB;  // 391
    const int agg_blocks = (N_NODES * 64 + TPB - 1) / TPB;               // 12500

    // ---- layer 0: 1280 -> 128 ----
    gemm_x_f16<<<gemm_blocks, TPB, 0, stream>>>(x, W0t, hA16, N_NODES, 1280);
    aggregate<128><<<agg_blocks, TPB, 0, stream>>>(hA16, rowstart, csr_src, csr_norm, dinv, bg0, hB);
    hipMemsetAsync(bnstat, 0, 2 * 128 * 4, stream);
    bn_stats<128><<<(N_NODES + 127) / 128, 128, 0, stream>>>(hB, bnstat);
    bn_finalize<128><<<1, 128, 0, stream>>>(bnstat, gamma0, beta0, bnss);
    bn_apply_relu<128><<<(N_NODES * 128) / 256, 256, 0, stream>>>(hB, bnss, h16);

    // ---- layer 1: 128 -> 256 ----
    gemm_h_f16<128><<<dim3(gemm_blocks, 2), TPB, 0, stream>>>(h16, W1t, hA16, N_NODES, 256);
    aggregate<256><<<agg_blocks, TPB, 0, stream>>>(hA16, rowstart, csr_src, csr_norm, dinv, bg1, hB);
    hipMemsetAsync(bnstat, 0, 2 * 256 * 4, stream);
    bn_stats<256><<<(N_NODES + 127) / 128, 256, 0, stream>>>(hB, bnstat);
    bn_finalize<256><<<1, 256, 0, stream>>>(bnstat, gamma1, beta1, bnss);
    bn_apply_relu<256><<<(N_NODES * 256) / 256, 256, 0, stream>>>(hB, bnss, h16);

    // ---- layer 2: 256 -> 256 ----
    gemm_h_f16<256><<<dim3(gemm_blocks, 2), TPB, 0, stream>>>(h16, W2t, hA16, N_NODES, 256);
    aggregate<256><<<agg_blocks, TPB, 0, stream>>>(hA16, rowstart, csr_src, csr_norm, dinv, bg2, hB);
    hipMemsetAsync(bnstat, 0, 2 * 256 * 4, stream);
    bn_stats<256><<<(N_NODES + 127) / 128, 256, 0, stream>>>(hB, bnstat);
    bn_finalize<256><<<1, 256, 0, stream>>>(bnstat, gamma2, beta2, bnss);
    bn_apply_relu<256><<<(N_NODES * 256) / 256, 256, 0, stream>>>(hB, bnss, h16);

    // ---- global mean pool ----
    hipMemsetAsync(psum, 0, 64 * 256 * 4, stream);
    count_batch_bs<<<1, 64, 0, stream>>>(batch, pcount);
    pool_seg<<<(N_NODES + 63) / 64, 256, 0, stream>>>(hB, batch, psum);
    pool_div<<<64, 256, 0, stream>>>(psum, pcount, gpool);

    // ---- FC head (split-K, atomic accumulate) ----
    fc_init<<<(64 * 1024 + 255) / 256, 256, 0, stream>>>(bf0, g1, 64, 1024);
    fc_splitk<<<dim3(4, 64, 4), 256, 0, stream>>>(gpool, Wf0, g1, 256, 1024, 64);
    relu_inplace<<<(64 * 1024 + 255) / 256, 256, 0, stream>>>(g1, 64 * 1024);
    fc_init<<<(64 * 128 + 255) / 256, 256, 0, stream>>>(bf1, out, 64, 128);
    fc_splitk<<<dim3(1, 64, 16), 128, 0, stream>>>(g1, Wf1, out, 1024, 128, 64);
}

// Round 6
// 1128.863 us; speedup vs baseline: 1.9482x; 1.0503x over previous
//
#include <hip/hip_runtime.h>
#include <hip/hip_bf16.h>

#define N_NODES 50000
#define N_EDGES 1600000
#define N_GRAPHS 64

typedef _Float16 f16;
typedef _Float16 f16x8 __attribute__((ext_vector_type(8)));
typedef _Float16 f16x4 __attribute__((ext_vector_type(4)));
typedef float f32x4 __attribute__((ext_vector_type(4)));

// ---------------------------------------------------------------------------
// Graph-structure construction
// ---------------------------------------------------------------------------
__global__ void init_deg(int* deg) {
    int i = blockIdx.x * blockDim.x + threadIdx.x;
    if (i < N_NODES) deg[i] = 1;  // self-loop
}

__global__ void deg_count(const int* __restrict__ dst, int* __restrict__ deg) {
    int e = blockIdx.x * blockDim.x + threadIdx.x;
    if (e < N_EDGES) atomicAdd(&deg[dst[e]], 1);
}

__global__ void make_dinv(const int* __restrict__ deg, float* __restrict__ dinv) {
    int i = blockIdx.x * blockDim.x + threadIdx.x;
    if (i < N_NODES) dinv[i] = rsqrtf((float)deg[i]);
}

// single-block scan over edge-only degrees -> rowstart[N+1], pos[N]
__global__ void scan_deg(const int* __restrict__ deg, int* __restrict__ rowstart,
                         int* __restrict__ pos) {
    __shared__ int wsum[16];
    __shared__ int carry_s;
    const int t = threadIdx.x;
    const int lane = t & 63;
    const int w = t >> 6;
    if (t == 0) carry_s = 0;
    __syncthreads();
    for (int base = 0; base < N_NODES; base += 1024) {
        int i = base + t;
        int v = (i < N_NODES) ? (deg[i] - 1) : 0;  // exclude self loop
        int s = v;
#pragma unroll
        for (int off = 1; off < 64; off <<= 1) {
            int n = __shfl_up(s, off, 64);
            if (lane >= off) s += n;
        }
        if (lane == 63) wsum[w] = s;
        __syncthreads();
        if (w == 0) {
            int ws = (lane < 16) ? wsum[lane] : 0;
#pragma unroll
            for (int off = 1; off < 16; off <<= 1) {
                int n = __shfl_up(ws, off, 64);
                if (lane >= off) ws += n;
            }
            if (lane < 16) wsum[lane] = ws;
        }
        __syncthreads();
        int waveoff = (w == 0) ? 0 : wsum[w - 1];
        int carry = carry_s;
        int excl = carry + waveoff + s - v;
        if (i < N_NODES) {
            rowstart[i] = excl;
            pos[i] = excl;
        }
        __syncthreads();
        if (t == 0) carry_s = carry + wsum[15];
        __syncthreads();
    }
    if (t == 0) rowstart[N_NODES] = carry_s;
}

__global__ void csr_fill(const int* __restrict__ src, const int* __restrict__ dst,
                         const float* __restrict__ dinv, int* __restrict__ pos,
                         int* __restrict__ csr_src, float* __restrict__ csr_norm) {
    int e = blockIdx.x * blockDim.x + threadIdx.x;
    if (e >= N_EDGES) return;
    int s = src[e], d = dst[e];
    int slot = atomicAdd(&pos[d], 1);
    csr_src[slot] = s;
    csr_norm[slot] = dinv[s] * dinv[d];
}

// ---------------------------------------------------------------------------
// Weight cast+transpose: Wt[n][k] = (f16) W[k][n]
// ---------------------------------------------------------------------------
__global__ void cast_w(const float* __restrict__ W, f16* __restrict__ Wt, int K, int N) {
    int i = blockIdx.x * blockDim.x + threadIdx.x;
    if (i >= K * N) return;
    int k = i % K, n = i / K;
    Wt[i] = (f16)W[(size_t)k * N + n];
}

// ---------------------------------------------------------------------------
// MFMA GEMM layer 0, split-K=2: A[M,K] fp32 (cast in-register), Bt[128][K] f16.
// Wave gw: row-tile gw>>1 (32 rows), split gw&1 -> K half. fp32 partials, no atomics.
// ---------------------------------------------------------------------------
__launch_bounds__(256)
__global__ void gemm_x_f16_sk(const float* __restrict__ A, const f16* __restrict__ Bt,
                              float* __restrict__ C0, float* __restrict__ C1, int M, int K) {
    const int gw = (int)((blockIdx.x * blockDim.x + threadIdx.x) >> 6);
    const int lane = threadIdx.x & 63;
    const int tile = gw >> 1, s = gw & 1;
    const int m0 = tile * 32;
    if (m0 >= M) return;
    float* __restrict__ C = s ? C1 : C0;
    const int KC = K >> 1;
    const int kbeg = s * KC;
    const int r = lane & 15, q = lane >> 4;
    int row0 = m0 + r;       int row0c = row0 < M ? row0 : M - 1;
    int row1 = m0 + 16 + r;  int row1c = row1 < M ? row1 : M - 1;
    const float* a0 = A + (size_t)row0c * K + q * 8;
    const float* a1 = A + (size_t)row1c * K + q * 8;
    const f16* bp = Bt + (size_t)r * K + q * 8;

    f32x4 acc[2][8];
#pragma unroll
    for (int i = 0; i < 2; ++i)
#pragma unroll
        for (int j = 0; j < 8; ++j) acc[i][j] = (f32x4){0.f, 0.f, 0.f, 0.f};

    for (int k0 = kbeg; k0 < kbeg + KC; k0 += 32) {
        f16x8 af[2];
        {
            float4 u = *(const float4*)(a0 + k0);
            float4 v = *(const float4*)(a0 + k0 + 4);
            af[0] = (f16x8){(f16)u.x, (f16)u.y, (f16)u.z, (f16)u.w,
                            (f16)v.x, (f16)v.y, (f16)v.z, (f16)v.w};
            u = *(const float4*)(a1 + k0);
            v = *(const float4*)(a1 + k0 + 4);
            af[1] = (f16x8){(f16)u.x, (f16)u.y, (f16)u.z, (f16)u.w,
                            (f16)v.x, (f16)v.y, (f16)v.z, (f16)v.w};
        }
#pragma unroll
        for (int ni = 0; ni < 8; ++ni) {
            f16x8 bf = *(const f16x8*)(bp + (size_t)ni * 16 * K + k0);
            acc[0][ni] = __builtin_amdgcn_mfma_f32_16x16x32_f16(af[0], bf, acc[0][ni], 0, 0, 0);
            acc[1][ni] = __builtin_amdgcn_mfma_f32_16x16x32_f16(af[1], bf, acc[1][ni], 0, 0, 0);
        }
    }
#pragma unroll
    for (int mi = 0; mi < 2; ++mi)
#pragma unroll
        for (int j = 0; j < 4; ++j) {
            int row = m0 + mi * 16 + q * 4 + j;
            if (row < M) {
                float* cp = C + (size_t)row * 128 + r;
#pragma unroll
                for (int ni = 0; ni < 8; ++ni) cp[ni * 16] = acc[mi][ni][j];
            }
        }
}

// sum split-K partials, cast to f16 (vectorized x4)
__global__ void reduce_cast(const float* __restrict__ c0, const float* __restrict__ c1,
                            f16* __restrict__ o, int n4) {
    int i = blockIdx.x * blockDim.x + threadIdx.x;
    if (i >= n4) return;
    float4 a = ((const float4*)c0)[i];
    float4 b = ((const float4*)c1)[i];
    f16x4 r = {(f16)(a.x + b.x), (f16)(a.y + b.y), (f16)(a.z + b.z), (f16)(a.w + b.w)};
    ((f16x4*)o)[i] = r;
}

// ---------------------------------------------------------------------------
// MFMA GEMM, layers 1/2: A16[M,K] f16, Bt[N][K] f16, C16[M,N] f16.
// ---------------------------------------------------------------------------
template <int K>
__launch_bounds__(256)
__global__ void gemm_h_f16(const f16* __restrict__ A16, const f16* __restrict__ Bt,
                           f16* __restrict__ C16, int M, int N) {
    const int wave = (int)((blockIdx.x * blockDim.x + threadIdx.x) >> 6);
    const int lane = threadIdx.x & 63;
    const int m0 = wave * 32;
    if (m0 >= M) return;
    const int col0 = blockIdx.y * 128;
    const int r = lane & 15, q = lane >> 4;
    int row0 = m0 + r;       int row0c = row0 < M ? row0 : M - 1;
    int row1 = m0 + 16 + r;  int row1c = row1 < M ? row1 : M - 1;
    const f16* a0 = A16 + (size_t)row0c * K + q * 8;
    const f16* a1 = A16 + (size_t)row1c * K + q * 8;
    const f16* bp = Bt + (size_t)(col0 + r) * K + q * 8;

    f32x4 acc[2][8];
#pragma unroll
    for (int i = 0; i < 2; ++i)
#pragma unroll
        for (int j = 0; j < 8; ++j) acc[i][j] = (f32x4){0.f, 0.f, 0.f, 0.f};

#pragma unroll
    for (int k0 = 0; k0 < K; k0 += 32) {
        f16x8 af0 = *(const f16x8*)(a0 + k0);
        f16x8 af1 = *(const f16x8*)(a1 + k0);
#pragma unroll
        for (int ni = 0; ni < 8; ++ni) {
            f16x8 bf = *(const f16x8*)(bp + (size_t)ni * 16 * K + k0);
            acc[0][ni] = __builtin_amdgcn_mfma_f32_16x16x32_f16(af0, bf, acc[0][ni], 0, 0, 0);
            acc[1][ni] = __builtin_amdgcn_mfma_f32_16x16x32_f16(af1, bf, acc[1][ni], 0, 0, 0);
        }
    }
#pragma unroll
    for (int mi = 0; mi < 2; ++mi)
#pragma unroll
        for (int j = 0; j < 4; ++j) {
            int row = m0 + mi * 16 + q * 4 + j;
            if (row < M) {
                f16* cp = C16 + (size_t)row * N + col0 + r;
#pragma unroll
                for (int ni = 0; ni < 8; ++ni) cp[ni * 16] = (f16)acc[mi][ni][j];
            }
        }
}

// ---------------------------------------------------------------------------
// Edge aggregation (f16 gather, fp32 accumulate, f16 out): one wave per node.
// ---------------------------------------------------------------------------
template <int D>
__launch_bounds__(256)
__global__ void aggregate(const f16* __restrict__ h, const int* __restrict__ rowstart,
                          const int* __restrict__ csr_src, const float* __restrict__ csr_norm,
                          const float* __restrict__ dinv, const float* __restrict__ bias,
                          f16* __restrict__ out) {
    constexpr int V = D / 64;  // f16 per lane (2 or 4)
    int w = (int)((blockIdx.x * blockDim.x + threadIdx.x) >> 6);
    int lane = threadIdx.x & 63;
    if (w >= N_NODES) return;
    float acc[V];
    float di = dinv[w];
    const f16* hp = h + (size_t)w * D + lane * V;
#pragma unroll
    for (int v = 0; v < V; ++v) acc[v] = (float)hp[v] * (di * di);
    int e0 = rowstart[w], e1 = rowstart[w + 1];
    for (int j = e0; j < e1; ++j) {
        int s = csr_src[j];
        float nm = csr_norm[j];
        const f16* sp = h + (size_t)s * D + lane * V;
#pragma unroll
        for (int v = 0; v < V; ++v) acc[v] += (float)sp[v] * nm;
    }
    f16* op = out + (size_t)w * D + lane * V;
#pragma unroll
    for (int v = 0; v < V; ++v) op[v] = (f16)(acc[v] + bias[lane * V + v]);
}

// ---------------------------------------------------------------------------
// BatchNorm (training stats, biased var) + ReLU — f16 in/out
// ---------------------------------------------------------------------------
template <int D>
__global__ void bn_stats(const f16* __restrict__ h, float* __restrict__ stat) {
    int f = threadIdx.x;  // D threads
    int r0 = blockIdx.x * 128;
    int r1 = min(r0 + 128, N_NODES);
    float s = 0.f, s2 = 0.f;
    for (int r = r0; r < r1; ++r) {
        float v = (float)h[(size_t)r * D + f];
        s += v;
        s2 += v * v;
    }
    atomicAdd(&stat[f], s);
    atomicAdd(&stat[D + f], s2);
}

template <int D>
__global__ void bn_finalize(const float* __restrict__ stat, const float* __restrict__ gamma,
                            const float* __restrict__ beta, float* __restrict__ ss) {
    int f = threadIdx.x;
    float m = stat[f] * (1.0f / N_NODES);
    float var = stat[D + f] * (1.0f / N_NODES) - m * m;
    float sc = gamma[f] * rsqrtf(var + 1e-5f);
    ss[f] = sc;
    ss[D + f] = beta[f] - m * sc;
}

template <int D>
__global__ void bn_apply_relu(const f16* __restrict__ hin, const float* __restrict__ ss,
                              f16* __restrict__ hout) {
    int i = blockIdx.x * blockDim.x + threadIdx.x;  // 8 f16 per thread
    if (i >= N_NODES * D / 8) return;
    int f0 = (i * 8) & (D - 1);
    f16x8 v = ((const f16x8*)hin)[i];
    f16x8 r;
#pragma unroll
    for (int j = 0; j < 8; ++j) {
        float val = (float)v[j] * ss[f0 + j] + ss[D + f0 + j];
        r[j] = (f16)(val > 0.f ? val : 0.f);
    }
    ((f16x8*)hout)[i] = r;
}

// ---------------------------------------------------------------------------
// Pool (batch is sorted) + FC head
// ---------------------------------------------------------------------------
__global__ void count_batch_bs(const int* __restrict__ batch, int* __restrict__ cnt) {
    int g = threadIdx.x;  // one block, 64 threads
    if (g >= N_GRAPHS) return;
    int lo = 0, hi = N_NODES;
    while (lo < hi) { int mid = (lo + hi) >> 1; if (batch[mid] < g) lo = mid + 1; else hi = mid; }
    int b0 = lo;
    lo = 0; hi = N_NODES;
    while (lo < hi) { int mid = (lo + hi) >> 1; if (batch[mid] < g + 1) lo = mid + 1; else hi = mid; }
    cnt[g] = lo - b0;
}

__global__ void pool_seg(const f16* __restrict__ h, const int* __restrict__ batch,
                         float* __restrict__ psum) {
    int f = threadIdx.x;  // 256
    int r0 = blockIdx.x * 64;
    int r1 = min(r0 + 64, N_NODES);
    float acc = 0.f;
    int cur = batch[r0];
    for (int r = r0; r < r1; ++r) {
        int b = batch[r];
        if (b != cur) {
            atomicAdd(&psum[cur * 256 + f], acc);
            acc = 0.f;
            cur = b;
        }
        acc += (float)h[(size_t)r * 256 + f];
    }
    atomicAdd(&psum[cur * 256 + f], acc);
}

__global__ void pool_div(const float* __restrict__ psum, const int* __restrict__ cnt,
                         float* __restrict__ g) {
    int i = blockIdx.x * 256 + threadIdx.x;  // 64*256
    int b = i >> 8;
    float c = (float)max(cnt[b], 1);
    g[i] = psum[i] / c;
}

// ---- FC head: split-K with atomic accumulation (high TLP) ----
__global__ void fc_init(const float* __restrict__ b, float* __restrict__ Y, int rows, int N) {
    int i = blockIdx.x * blockDim.x + threadIdx.x;
    if (i < rows * N) Y[i] = b[i % N];
}

__global__ void fc_splitk(const float* __restrict__ X, const float* __restrict__ W,
                          float* __restrict__ Y, int K, int N, int KC) {
    int col = blockIdx.x * blockDim.x + threadIdx.x;
    int row = blockIdx.y;
    int k0 = blockIdx.z * KC;
    float acc = 0.f;
    const float* x = X + (size_t)row * K + k0;
    const float* w = W + (size_t)k0 * N + col;
#pragma unroll 8
    for (int k = 0; k < KC; ++k) acc += x[k] * w[(size_t)k * N];
    atomicAdd(&Y[(size_t)row * N + col], acc);
}

__global__ void relu_inplace(float* __restrict__ Y, int n) {
    int i = blockIdx.x * blockDim.x + threadIdx.x;
    if (i < n) Y[i] = Y[i] > 0.f ? Y[i] : 0.f;
}

// ---------------------------------------------------------------------------
extern "C" void kernel_launch(void* const* d_in, const int* in_sizes, int n_in,
                              void* d_out, int out_size, void* d_ws, size_t ws_size,
                              hipStream_t stream) {
    const float* x     = (const float*)d_in[0];
    const int*   ei    = (const int*)d_in[1];   // [2][E]: row0=src, row1=dst
    const int*   batch = (const int*)d_in[2];
    const float* Wg0 = (const float*)d_in[3],  *bg0 = (const float*)d_in[4];
    const float* gamma0 = (const float*)d_in[5], *beta0 = (const float*)d_in[6];
    const float* Wg1 = (const float*)d_in[7],  *bg1 = (const float*)d_in[8];
    const float* gamma1 = (const float*)d_in[9], *beta1 = (const float*)d_in[10];
    const float* Wg2 = (const float*)d_in[11], *bg2 = (const float*)d_in[12];
    const float* gamma2 = (const float*)d_in[13], *beta2 = (const float*)d_in[14];
    const float* Wf0 = (const float*)d_in[15], *bf0 = (const float*)d_in[16];
    const float* Wf1 = (const float*)d_in[17], *bf1 = (const float*)d_in[18];
    float* out = (float*)d_out;

    // ---- workspace carve (~117 MB, split-K partials alias f16 intermediates) ----
    size_t off = 0;
    auto alloc = [&](size_t bytes) {
        void* p = (char*)d_ws + off;
        off += (bytes + 255) & ~(size_t)255;
        return p;
    };
    f16*   hA16     = (f16*)alloc((size_t)N_NODES * 256 * 2);   // GEMM out (gather src)
    float* cp32     = (float*)alloc((size_t)N_NODES * 256 * 4); // split-K partials (layer 0 only)
    f16*   hBn16    = (f16*)cp32;                                // agg out  (lower 25.6MB)
    f16*   h16      = (f16*)(cp32 + (size_t)N_NODES * 128);     // BN out   (upper 25.6MB)
    float* cp0      = cp32;
    float* cp1      = cp32 + (size_t)N_NODES * 128;
    int*   csr_src  = (int*)alloc((size_t)N_EDGES * 4);
    float* csr_norm = (float*)alloc((size_t)N_EDGES * 4);
    int*   deg      = (int*)alloc((size_t)N_NODES * 4);
    float* dinv     = (float*)alloc((size_t)N_NODES * 4);
    int*   rowstart = (int*)alloc((size_t)(N_NODES + 1) * 4);
    int*   pos      = (int*)alloc((size_t)N_NODES * 4);
    float* bnstat   = (float*)alloc(2 * 256 * 4);
    float* bnss     = (float*)alloc(2 * 256 * 4);
    float* psum     = (float*)alloc(64 * 256 * 4);
    int*   pcount   = (int*)alloc(64 * 4);
    float* gpool    = (float*)alloc(64 * 256 * 4);
    float* g1       = (float*)alloc(64 * 1024 * 4);
    f16*   W0t      = (f16*)alloc((size_t)1280 * 128 * 2);
    f16*   W1t      = (f16*)alloc((size_t)128 * 256 * 2);
    f16*   W2t      = (f16*)alloc((size_t)256 * 256 * 2);
    (void)ws_size;

    const int TPB = 256;
    const int nb_nodes = (N_NODES + TPB - 1) / TPB;
    const int nb_edges = (N_EDGES + TPB - 1) / TPB;

    // ---- graph structure + weight casts ----
    init_deg<<<nb_nodes, TPB, 0, stream>>>(deg);
    deg_count<<<nb_edges, TPB, 0, stream>>>(ei + N_EDGES, deg);
    make_dinv<<<nb_nodes, TPB, 0, stream>>>(deg, dinv);
    scan_deg<<<1, 1024, 0, stream>>>(deg, rowstart, pos);
    csr_fill<<<nb_edges, TPB, 0, stream>>>(ei, ei + N_EDGES, dinv, pos, csr_src, csr_norm);
    cast_w<<<(1280 * 128 + 255) / 256, 256, 0, stream>>>(Wg0, W0t, 1280, 128);
    cast_w<<<(128 * 256 + 255) / 256, 256, 0, stream>>>(Wg1, W1t, 128, 256);
    cast_w<<<(256 * 256 + 255) / 256, 256, 0, stream>>>(Wg2, W2t, 256, 256);

    const int gemm_blocks = ((N_NODES + 31) / 32 * 64 + TPB - 1) / TPB;       // 391
    const int gemm_sk_blocks = ((N_NODES + 31) / 32 * 2 * 64 + TPB - 1) / TPB; // 782
    const int agg_blocks = (N_NODES * 64 + TPB - 1) / TPB;                     // 12500

    // ---- layer 0: 1280 -> 128 (split-K=2) ----
    gemm_x_f16_sk<<<gemm_sk_blocks, TPB, 0, stream>>>(x, W0t, cp0, cp1, N_NODES, 1280);
    reduce_cast<<<(N_NODES * 128 / 4 + 255) / 256, 256, 0, stream>>>(cp0, cp1, hA16, N_NODES * 128 / 4);
    aggregate<128><<<agg_blocks, TPB, 0, stream>>>(hA16, rowstart, csr_src, csr_norm, dinv, bg0, hBn16);
    hipMemsetAsync(bnstat, 0, 2 * 128 * 4, stream);
    bn_stats<128><<<(N_NODES + 127) / 128, 128, 0, stream>>>(hBn16, bnstat);
    bn_finalize<128><<<1, 128, 0, stream>>>(bnstat, gamma0, beta0, bnss);
    bn_apply_relu<128><<<(N_NODES * 128 / 8 + 255) / 256, 256, 0, stream>>>(hBn16, bnss, h16);

    // ---- layer 1: 128 -> 256 ----
    gemm_h_f16<128><<<dim3(gemm_blocks, 2), TPB, 0, stream>>>(h16, W1t, hA16, N_NODES, 256);
    aggregate<256><<<agg_blocks, TPB, 0, stream>>>(hA16, rowstart, csr_src, csr_norm, dinv, bg1, hBn16);
    hipMemsetAsync(bnstat, 0, 2 * 256 * 4, stream);
    bn_stats<256><<<(N_NODES + 127) / 128, 256, 0, stream>>>(hBn16, bnstat);
    bn_finalize<256><<<1, 256, 0, stream>>>(bnstat, gamma1, beta1, bnss);
    bn_apply_relu<256><<<(N_NODES * 256 / 8 + 255) / 256, 256, 0, stream>>>(hBn16, bnss, h16);

    // ---- layer 2: 256 -> 256 ----
    gemm_h_f16<256><<<dim3(gemm_blocks, 2), TPB, 0, stream>>>(h16, W2t, hA16, N_NODES, 256);
    aggregate<256><<<agg_blocks, TPB, 0, stream>>>(hA16, rowstart, csr_src, csr_norm, dinv, bg2, hBn16);
    hipMemsetAsync(bnstat, 0, 2 * 256 * 4, stream);
    bn_stats<256><<<(N_NODES + 127) / 128, 256, 0, stream>>>(hBn16, bnstat);
    bn_finalize<256><<<1, 256, 0, stream>>>(bnstat, gamma2, beta2, bnss);
    bn_apply_relu<256><<<(N_NODES * 256 / 8 + 255) / 256, 256, 0, stream>>>(hBn16, bnss, h16);

    // ---- global mean pool ----
    hipMemsetAsync(psum, 0, 64 * 256 * 4, stream);
    count_batch_bs<<<1, 64, 0, stream>>>(batch, pcount);
    pool_seg<<<(N_NODES + 63) / 64, 256, 0, stream>>>(h16, batch, psum);
    pool_div<<<64, 256, 0, stream>>>(psum, pcount, gpool);

    // ---- FC head (split-K, atomic accumulate) ----
    fc_init<<<(64 * 1024 + 255) / 256, 256, 0, stream>>>(bf0, g1, 64, 1024);
    fc_splitk<<<dim3(4, 64, 4), 256, 0, stream>>>(gpool, Wf0, g1, 256, 1024, 64);
    relu_inplace<<<(64 * 1024 + 255) / 256, 256, 0, stream>>>(g1, 64 * 1024);
    fc_init<<<(64 * 128 + 255) / 256, 256, 0, stream>>>(bf1, out, 64, 128);
    fc_splitk<<<dim3(1, 64, 16), 128, 0, stream>>>(g1, Wf1, out, 1024, 128, 64);
}

// Round 7
// 900.390 us; speedup vs baseline: 2.4425x; 1.2537x over previous
//
#include <hip/hip_runtime.h>
#include <hip/hip_bf16.h>

#define N_NODES 50000
#define N_EDGES 1600000
#define N_GRAPHS 64

typedef _Float16 f16;
typedef _Float16 f16x8 __attribute__((ext_vector_type(8)));
typedef _Float16 f16x4 __attribute__((ext_vector_type(4)));
typedef _Float16 f16x2 __attribute__((ext_vector_type(2)));
typedef float f32x4 __attribute__((ext_vector_type(4)));

template <int V> struct VecT;
template <> struct VecT<2> { using type = f16x2; };
template <> struct VecT<4> { using type = f16x4; };

// ---------------------------------------------------------------------------
// Graph-structure construction
// ---------------------------------------------------------------------------
__global__ void init_deg(int* deg) {
    int i = blockIdx.x * blockDim.x + threadIdx.x;
    if (i < N_NODES) deg[i] = 1;  // self-loop
}

__global__ void deg_count(const int* __restrict__ dst, int* __restrict__ deg) {
    int e = blockIdx.x * blockDim.x + threadIdx.x;
    if (e < N_EDGES) atomicAdd(&deg[dst[e]], 1);
}

__global__ void make_dinv(const int* __restrict__ deg, float* __restrict__ dinv) {
    int i = blockIdx.x * blockDim.x + threadIdx.x;
    if (i < N_NODES) dinv[i] = rsqrtf((float)deg[i]);
}

// single-block scan over edge-only degrees -> rowstart[N+1], pos[N]
__global__ void scan_deg(const int* __restrict__ deg, int* __restrict__ rowstart,
                         int* __restrict__ pos) {
    __shared__ int wsum[16];
    __shared__ int carry_s;
    const int t = threadIdx.x;
    const int lane = t & 63;
    const int w = t >> 6;
    if (t == 0) carry_s = 0;
    __syncthreads();
    for (int base = 0; base < N_NODES; base += 1024) {
        int i = base + t;
        int v = (i < N_NODES) ? (deg[i] - 1) : 0;  // exclude self loop
        int s = v;
#pragma unroll
        for (int off = 1; off < 64; off <<= 1) {
            int n = __shfl_up(s, off, 64);
            if (lane >= off) s += n;
        }
        if (lane == 63) wsum[w] = s;
        __syncthreads();
        if (w == 0) {
            int ws = (lane < 16) ? wsum[lane] : 0;
#pragma unroll
            for (int off = 1; off < 16; off <<= 1) {
                int n = __shfl_up(ws, off, 64);
                if (lane >= off) ws += n;
            }
            if (lane < 16) wsum[lane] = ws;
        }
        __syncthreads();
        int waveoff = (w == 0) ? 0 : wsum[w - 1];
        int carry = carry_s;
        int excl = carry + waveoff + s - v;
        if (i < N_NODES) {
            rowstart[i] = excl;
            pos[i] = excl;
        }
        __syncthreads();
        if (t == 0) carry_s = carry + wsum[15];
        __syncthreads();
    }
    if (t == 0) rowstart[N_NODES] = carry_s;
}

// packed CSR entry: .x = src node, .y = norm (float bits)
__global__ void csr_fill(const int* __restrict__ src, const int* __restrict__ dst,
                         const float* __restrict__ dinv, int* __restrict__ pos,
                         int2* __restrict__ csr) {
    int e = blockIdx.x * blockDim.x + threadIdx.x;
    if (e >= N_EDGES) return;
    int s = src[e], d = dst[e];
    int slot = atomicAdd(&pos[d], 1);
    csr[slot] = make_int2(s, __float_as_int(dinv[s] * dinv[d]));
}

// ---------------------------------------------------------------------------
// Weight cast+transpose: Wt[n][k] = (f16) W[k][n]
// ---------------------------------------------------------------------------
__global__ void cast_w(const float* __restrict__ W, f16* __restrict__ Wt, int K, int N) {
    int i = blockIdx.x * blockDim.x + threadIdx.x;
    if (i >= K * N) return;
    int k = i % K, n = i / K;
    Wt[i] = (f16)W[(size_t)k * N + n];
}

// ---------------------------------------------------------------------------
// MFMA GEMM layer 0, split-K=2: A[M,K] fp32 (cast in-register), Bt[128][K] f16.
// ---------------------------------------------------------------------------
__launch_bounds__(256)
__global__ void gemm_x_f16_sk(const float* __restrict__ A, const f16* __restrict__ Bt,
                              float* __restrict__ C0, float* __restrict__ C1, int M, int K) {
    const int gw = (int)((blockIdx.x * blockDim.x + threadIdx.x) >> 6);
    const int lane = threadIdx.x & 63;
    const int tile = gw >> 1, s = gw & 1;
    const int m0 = tile * 32;
    if (m0 >= M) return;
    float* __restrict__ C = s ? C1 : C0;
    const int KC = K >> 1;
    const int kbeg = s * KC;
    const int r = lane & 15, q = lane >> 4;
    int row0 = m0 + r;       int row0c = row0 < M ? row0 : M - 1;
    int row1 = m0 + 16 + r;  int row1c = row1 < M ? row1 : M - 1;
    const float* a0 = A + (size_t)row0c * K + q * 8;
    const float* a1 = A + (size_t)row1c * K + q * 8;
    const f16* bp = Bt + (size_t)r * K + q * 8;

    f32x4 acc[2][8];
#pragma unroll
    for (int i = 0; i < 2; ++i)
#pragma unroll
        for (int j = 0; j < 8; ++j) acc[i][j] = (f32x4){0.f, 0.f, 0.f, 0.f};

    for (int k0 = kbeg; k0 < kbeg + KC; k0 += 32) {
        f16x8 af[2];
        {
            float4 u = *(const float4*)(a0 + k0);
            float4 v = *(const float4*)(a0 + k0 + 4);
            af[0] = (f16x8){(f16)u.x, (f16)u.y, (f16)u.z, (f16)u.w,
                            (f16)v.x, (f16)v.y, (f16)v.z, (f16)v.w};
            u = *(const float4*)(a1 + k0);
            v = *(const float4*)(a1 + k0 + 4);
            af[1] = (f16x8){(f16)u.x, (f16)u.y, (f16)u.z, (f16)u.w,
                            (f16)v.x, (f16)v.y, (f16)v.z, (f16)v.w};
        }
#pragma unroll
        for (int ni = 0; ni < 8; ++ni) {
            f16x8 bf = *(const f16x8*)(bp + (size_t)ni * 16 * K + k0);
            acc[0][ni] = __builtin_amdgcn_mfma_f32_16x16x32_f16(af[0], bf, acc[0][ni], 0, 0, 0);
            acc[1][ni] = __builtin_amdgcn_mfma_f32_16x16x32_f16(af[1], bf, acc[1][ni], 0, 0, 0);
        }
    }
#pragma unroll
    for (int mi = 0; mi < 2; ++mi)
#pragma unroll
        for (int j = 0; j < 4; ++j) {
            int row = m0 + mi * 16 + q * 4 + j;
            if (row < M) {
                float* cp = C + (size_t)row * 128 + r;
#pragma unroll
                for (int ni = 0; ni < 8; ++ni) cp[ni * 16] = acc[mi][ni][j];
            }
        }
}

// sum split-K partials, cast to f16 (vectorized x4)
__global__ void reduce_cast(const float* __restrict__ c0, const float* __restrict__ c1,
                            f16* __restrict__ o, int n4) {
    int i = blockIdx.x * blockDim.x + threadIdx.x;
    if (i >= n4) return;
    float4 a = ((const float4*)c0)[i];
    float4 b = ((const float4*)c1)[i];
    f16x4 r = {(f16)(a.x + b.x), (f16)(a.y + b.y), (f16)(a.z + b.z), (f16)(a.w + b.w)};
    ((f16x4*)o)[i] = r;
}

// ---------------------------------------------------------------------------
// MFMA GEMM, layers 1/2: A16[M,K] f16, Bt[N][K] f16, C16[M,N] f16.
// ---------------------------------------------------------------------------
template <int K>
__launch_bounds__(256)
__global__ void gemm_h_f16(const f16* __restrict__ A16, const f16* __restrict__ Bt,
                           f16* __restrict__ C16, int M, int N) {
    const int wave = (int)((blockIdx.x * blockDim.x + threadIdx.x) >> 6);
    const int lane = threadIdx.x & 63;
    const int m0 = wave * 32;
    if (m0 >= M) return;
    const int col0 = blockIdx.y * 128;
    const int r = lane & 15, q = lane >> 4;
    int row0 = m0 + r;       int row0c = row0 < M ? row0 : M - 1;
    int row1 = m0 + 16 + r;  int row1c = row1 < M ? row1 : M - 1;
    const f16* a0 = A16 + (size_t)row0c * K + q * 8;
    const f16* a1 = A16 + (size_t)row1c * K + q * 8;
    const f16* bp = Bt + (size_t)(col0 + r) * K + q * 8;

    f32x4 acc[2][8];
#pragma unroll
    for (int i = 0; i < 2; ++i)
#pragma unroll
        for (int j = 0; j < 8; ++j) acc[i][j] = (f32x4){0.f, 0.f, 0.f, 0.f};

#pragma unroll
    for (int k0 = 0; k0 < K; k0 += 32) {
        f16x8 af0 = *(const f16x8*)(a0 + k0);
        f16x8 af1 = *(const f16x8*)(a1 + k0);
#pragma unroll
        for (int ni = 0; ni < 8; ++ni) {
            f16x8 bf = *(const f16x8*)(bp + (size_t)ni * 16 * K + k0);
            acc[0][ni] = __builtin_amdgcn_mfma_f32_16x16x32_f16(af0, bf, acc[0][ni], 0, 0, 0);
            acc[1][ni] = __builtin_amdgcn_mfma_f32_16x16x32_f16(af1, bf, acc[1][ni], 0, 0, 0);
        }
    }
#pragma unroll
    for (int mi = 0; mi < 2; ++mi)
#pragma unroll
        for (int j = 0; j < 4; ++j) {
            int row = m0 + mi * 16 + q * 4 + j;
            if (row < M) {
                f16* cp = C16 + (size_t)row * N + col0 + r;
#pragma unroll
                for (int ni = 0; ni < 8; ++ni) cp[ni * 16] = (f16)acc[mi][ni][j];
            }
        }
}

// ---------------------------------------------------------------------------
// Edge aggregation (f16 gather, fp32 accumulate, f16 out): one wave per node.
// 4-deep unrolled gather loop -> 4 independent row-loads in flight (MLP).
// ---------------------------------------------------------------------------
template <int D>
__launch_bounds__(256)
__global__ void aggregate(const f16* __restrict__ h, const int* __restrict__ rowstart,
                          const int2* __restrict__ csr, const float* __restrict__ dinv,
                          const float* __restrict__ bias, f16* __restrict__ out) {
    constexpr int V = D / 64;  // f16 per lane (2 or 4)
    using vec = typename VecT<V>::type;
    int w = (int)((blockIdx.x * blockDim.x + threadIdx.x) >> 6);
    int lane = threadIdx.x & 63;
    if (w >= N_NODES) return;
    float acc[V];
    float di = dinv[w];
    vec self = *(const vec*)(h + (size_t)w * D + lane * V);
#pragma unroll
    for (int v = 0; v < V; ++v) acc[v] = (float)self[v] * (di * di);
    int e0 = rowstart[w], e1 = rowstart[w + 1];
    int j = e0;
    for (; j + 4 <= e1; j += 4) {
        int2 c0 = csr[j], c1 = csr[j + 1], c2 = csr[j + 2], c3 = csr[j + 3];
        vec r0 = *(const vec*)(h + (size_t)c0.x * D + lane * V);
        vec r1 = *(const vec*)(h + (size_t)c1.x * D + lane * V);
        vec r2 = *(const vec*)(h + (size_t)c2.x * D + lane * V);
        vec r3 = *(const vec*)(h + (size_t)c3.x * D + lane * V);
        float n0 = __int_as_float(c0.y), n1 = __int_as_float(c1.y);
        float n2 = __int_as_float(c2.y), n3 = __int_as_float(c3.y);
#pragma unroll
        for (int v = 0; v < V; ++v)
            acc[v] += (float)r0[v] * n0 + (float)r1[v] * n1 +
                      (float)r2[v] * n2 + (float)r3[v] * n3;
    }
    for (; j < e1; ++j) {
        int2 c = csr[j];
        vec r = *(const vec*)(h + (size_t)c.x * D + lane * V);
        float nm = __int_as_float(c.y);
#pragma unroll
        for (int v = 0; v < V; ++v) acc[v] += (float)r[v] * nm;
    }
    vec o;
#pragma unroll
    for (int v = 0; v < V; ++v) o[v] = (f16)(acc[v] + bias[lane * V + v]);
    *(vec*)(out + (size_t)w * D + lane * V) = o;
}

// ---------------------------------------------------------------------------
// BatchNorm (training stats, biased var) + ReLU — f16 in/out
// ---------------------------------------------------------------------------
template <int D>
__global__ void bn_stats(const f16* __restrict__ h, float* __restrict__ stat) {
    int f = threadIdx.x;  // D threads
    int r0 = blockIdx.x * 128;
    int r1 = min(r0 + 128, N_NODES);
    float s = 0.f, s2 = 0.f;
    for (int r = r0; r < r1; ++r) {
        float v = (float)h[(size_t)r * D + f];
        s += v;
        s2 += v * v;
    }
    atomicAdd(&stat[f], s);
    atomicAdd(&stat[D + f], s2);
}

template <int D>
__global__ void bn_finalize(const float* __restrict__ stat, const float* __restrict__ gamma,
                            const float* __restrict__ beta, float* __restrict__ ss) {
    int f = threadIdx.x;
    float m = stat[f] * (1.0f / N_NODES);
    float var = stat[D + f] * (1.0f / N_NODES) - m * m;
    float sc = gamma[f] * rsqrtf(var + 1e-5f);
    ss[f] = sc;
    ss[D + f] = beta[f] - m * sc;
}

template <int D>
__global__ void bn_apply_relu(const f16* __restrict__ hin, const float* __restrict__ ss,
                              f16* __restrict__ hout) {
    int i = blockIdx.x * blockDim.x + threadIdx.x;  // 8 f16 per thread
    if (i >= N_NODES * D / 8) return;
    int f0 = (i * 8) & (D - 1);
    f16x8 v = ((const f16x8*)hin)[i];
    f16x8 r;
#pragma unroll
    for (int j = 0; j < 8; ++j) {
        float val = (float)v[j] * ss[f0 + j] + ss[D + f0 + j];
        r[j] = (f16)(val > 0.f ? val : 0.f);
    }
    ((f16x8*)hout)[i] = r;
}

// ---------------------------------------------------------------------------
// Pool (batch is sorted) + FC head
// ---------------------------------------------------------------------------
__global__ void count_batch_bs(const int* __restrict__ batch, int* __restrict__ cnt) {
    int g = threadIdx.x;  // one block, 64 threads
    if (g >= N_GRAPHS) return;
    int lo = 0, hi = N_NODES;
    while (lo < hi) { int mid = (lo + hi) >> 1; if (batch[mid] < g) lo = mid + 1; else hi = mid; }
    int b0 = lo;
    lo = 0; hi = N_NODES;
    while (lo < hi) { int mid = (lo + hi) >> 1; if (batch[mid] < g + 1) lo = mid + 1; else hi = mid; }
    cnt[g] = lo - b0;
}

__global__ void pool_seg(const f16* __restrict__ h, const int* __restrict__ batch,
                         float* __restrict__ psum) {
    int f = threadIdx.x;  // 256
    int r0 = blockIdx.x * 64;
    int r1 = min(r0 + 64, N_NODES);
    float acc = 0.f;
    int cur = batch[r0];
    for (int r = r0; r < r1; ++r) {
        int b = batch[r];
        if (b != cur) {
            atomicAdd(&psum[cur * 256 + f], acc);
            acc = 0.f;
            cur = b;
        }
        acc += (float)h[(size_t)r * 256 + f];
    }
    atomicAdd(&psum[cur * 256 + f], acc);
}

__global__ void pool_div(const float* __restrict__ psum, const int* __restrict__ cnt,
                         float* __restrict__ g) {
    int i = blockIdx.x * 256 + threadIdx.x;  // 64*256
    int b = i >> 8;
    float c = (float)max(cnt[b], 1);
    g[i] = psum[i] / c;
}

// ---- FC head: split-K with atomic accumulation (high TLP) ----
__global__ void fc_init(const float* __restrict__ b, float* __restrict__ Y, int rows, int N) {
    int i = blockIdx.x * blockDim.x + threadIdx.x;
    if (i < rows * N) Y[i] = b[i % N];
}

__global__ void fc_splitk(const float* __restrict__ X, const float* __restrict__ W,
                          float* __restrict__ Y, int K, int N, int KC) {
    int col = blockIdx.x * blockDim.x + threadIdx.x;
    int row = blockIdx.y;
    int k0 = blockIdx.z * KC;
    float acc = 0.f;
    const float* x = X + (size_t)row * K + k0;
    const float* w = W + (size_t)k0 * N + col;
#pragma unroll 8
    for (int k = 0; k < KC; ++k) acc += x[k] * w[(size_t)k * N];
    atomicAdd(&Y[(size_t)row * N + col], acc);
}

__global__ void relu_inplace(float* __restrict__ Y, int n) {
    int i = blockIdx.x * blockDim.x + threadIdx.x;
    if (i < n) Y[i] = Y[i] > 0.f ? Y[i] : 0.f;
}

// ---------------------------------------------------------------------------
extern "C" void kernel_launch(void* const* d_in, const int* in_sizes, int n_in,
                              void* d_out, int out_size, void* d_ws, size_t ws_size,
                              hipStream_t stream) {
    const float* x     = (const float*)d_in[0];
    const int*   ei    = (const int*)d_in[1];   // [2][E]: row0=src, row1=dst
    const int*   batch = (const int*)d_in[2];
    const float* Wg0 = (const float*)d_in[3],  *bg0 = (const float*)d_in[4];
    const float* gamma0 = (const float*)d_in[5], *beta0 = (const float*)d_in[6];
    const float* Wg1 = (const float*)d_in[7],  *bg1 = (const float*)d_in[8];
    const float* gamma1 = (const float*)d_in[9], *beta1 = (const float*)d_in[10];
    const float* Wg2 = (const float*)d_in[11], *bg2 = (const float*)d_in[12];
    const float* gamma2 = (const float*)d_in[13], *beta2 = (const float*)d_in[14];
    const float* Wf0 = (const float*)d_in[15], *bf0 = (const float*)d_in[16];
    const float* Wf1 = (const float*)d_in[17], *bf1 = (const float*)d_in[18];
    float* out = (float*)d_out;

    // ---- workspace carve (~117 MB, split-K partials alias f16 intermediates) ----
    size_t off = 0;
    auto alloc = [&](size_t bytes) {
        void* p = (char*)d_ws + off;
        off += (bytes + 255) & ~(size_t)255;
        return p;
    };
    f16*   hA16     = (f16*)alloc((size_t)N_NODES * 256 * 2);   // GEMM out (gather src)
    float* cp32     = (float*)alloc((size_t)N_NODES * 256 * 4); // split-K partials (layer 0 only)
    f16*   hBn16    = (f16*)cp32;                                // agg out  (lower 25.6MB)
    f16*   h16      = (f16*)(cp32 + (size_t)N_NODES * 128);     // BN out   (upper 25.6MB)
    float* cp0      = cp32;
    float* cp1      = cp32 + (size_t)N_NODES * 128;
    int2*  csr      = (int2*)alloc((size_t)N_EDGES * 8);
    int*   deg      = (int*)alloc((size_t)N_NODES * 4);
    float* dinv     = (float*)alloc((size_t)N_NODES * 4);
    int*   rowstart = (int*)alloc((size_t)(N_NODES + 1) * 4);
    int*   pos      = (int*)alloc((size_t)N_NODES * 4);
    float* bnstat   = (float*)alloc(2 * 256 * 4);
    float* bnss     = (float*)alloc(2 * 256 * 4);
    float* psum     = (float*)alloc(64 * 256 * 4);
    int*   pcount   = (int*)alloc(64 * 4);
    float* gpool    = (float*)alloc(64 * 256 * 4);
    float* g1       = (float*)alloc(64 * 1024 * 4);
    f16*   W0t      = (f16*)alloc((size_t)1280 * 128 * 2);
    f16*   W1t      = (f16*)alloc((size_t)128 * 256 * 2);
    f16*   W2t      = (f16*)alloc((size_t)256 * 256 * 2);
    (void)ws_size;

    const int TPB = 256;
    const int nb_nodes = (N_NODES + TPB - 1) / TPB;
    const int nb_edges = (N_EDGES + TPB - 1) / TPB;

    // ---- graph structure + weight casts ----
    init_deg<<<nb_nodes, TPB, 0, stream>>>(deg);
    deg_count<<<nb_edges, TPB, 0, stream>>>(ei + N_EDGES, deg);
    make_dinv<<<nb_nodes, TPB, 0, stream>>>(deg, dinv);
    scan_deg<<<1, 1024, 0, stream>>>(deg, rowstart, pos);
    csr_fill<<<nb_edges, TPB, 0, stream>>>(ei, ei + N_EDGES, dinv, pos, csr);
    cast_w<<<(1280 * 128 + 255) / 256, 256, 0, stream>>>(Wg0, W0t, 1280, 128);
    cast_w<<<(128 * 256 + 255) / 256, 256, 0, stream>>>(Wg1, W1t, 128, 256);
    cast_w<<<(256 * 256 + 255) / 256, 256, 0, stream>>>(Wg2, W2t, 256, 256);

    const int gemm_blocks = ((N_NODES + 31) / 32 * 64 + TPB - 1) / TPB;        // 391
    const int gemm_sk_blocks = ((N_NODES + 31) / 32 * 2 * 64 + TPB - 1) / TPB; // 782
    const int agg_blocks = (N_NODES * 64 + TPB - 1) / TPB;                      // 12500

    // ---- layer 0: 1280 -> 128 (split-K=2) ----
    gemm_x_f16_sk<<<gemm_sk_blocks, TPB, 0, stream>>>(x, W0t, cp0, cp1, N_NODES, 1280);
    reduce_cast<<<(N_NODES * 128 / 4 + 255) / 256, 256, 0, stream>>>(cp0, cp1, hA16, N_NODES * 128 / 4);
    aggregate<128><<<agg_blocks, TPB, 0, stream>>>(hA16, rowstart, csr, dinv, bg0, hBn16);
    hipMemsetAsync(bnstat, 0, 2 * 128 * 4, stream);
    bn_stats<128><<<(N_NODES + 127) / 128, 128, 0, stream>>>(hBn16, bnstat);
    bn_finalize<128><<<1, 128, 0, stream>>>(bnstat, gamma0, beta0, bnss);
    bn_apply_relu<128><<<(N_NODES * 128 / 8 + 255) / 256, 256, 0, stream>>>(hBn16, bnss, h16);

    // ---- layer 1: 128 -> 256 ----
    gemm_h_f16<128><<<dim3(gemm_blocks, 2), TPB, 0, stream>>>(h16, W1t, hA16, N_NODES, 256);
    aggregate<256><<<agg_blocks, TPB, 0, stream>>>(hA16, rowstart, csr, dinv, bg1, hBn16);
    hipMemsetAsync(bnstat, 0, 2 * 256 * 4, stream);
    bn_stats<256><<<(N_NODES + 127) / 128, 256, 0, stream>>>(hBn16, bnstat);
    bn_finalize<256><<<1, 256, 0, stream>>>(bnstat, gamma1, beta1, bnss);
    bn_apply_relu<256><<<(N_NODES * 256 / 8 + 255) / 256, 256, 0, stream>>>(hBn16, bnss, h16);

    // ---- layer 2: 256 -> 256 ----
    gemm_h_f16<256><<<dim3(gemm_blocks, 2), TPB, 0, stream>>>(h16, W2t, hA16, N_NODES, 256);
    aggregate<256><<<agg_blocks, TPB, 0, stream>>>(hA16, rowstart, csr, dinv, bg2, hBn16);
    hipMemsetAsync(bnstat, 0, 2 * 256 * 4, stream);
    bn_stats<256><<<(N_NODES + 127) / 128, 256, 0, stream>>>(hBn16, bnstat);
    bn_finalize<256><<<1, 256, 0, stream>>>(bnstat, gamma2, beta2, bnss);
    bn_apply_relu<256><<<(N_NODES * 256 / 8 + 255) / 256, 256, 0, stream>>>(hBn16, bnss, h16);

    // ---- global mean pool ----
    hipMemsetAsync(psum, 0, 64 * 256 * 4, stream);
    count_batch_bs<<<1, 64, 0, stream>>>(batch, pcount);
    pool_seg<<<(N_NODES + 63) / 64, 256, 0, stream>>>(h16, batch, psum);
    pool_div<<<64, 256, 0, stream>>>(psum, pcount, gpool);

    // ---- FC head (split-K, atomic accumulate) ----
    fc_init<<<(64 * 1024 + 255) / 256, 256, 0, stream>>>(bf0, g1, 64, 1024);
    fc_splitk<<<dim3(4, 64, 4), 256, 0, stream>>>(gpool, Wf0, g1, 256, 1024, 64);
    relu_inplace<<<(64 * 1024 + 255) / 256, 256, 0, stream>>>(g1, 64 * 1024);
    fc_init<<<(64 * 128 + 255) / 256, 256, 0, stream>>>(bf1, out, 64, 128);
    fc_splitk<<<dim3(1, 64, 16), 128, 0, stream>>>(g1, Wf1, out, 1024, 128, 64);
}